// Round 1
// baseline (2035.176 us; speedup 1.0000x reference)
//
#include <hip/hip_runtime.h>
#include <math.h>

namespace {

constexpr int TS     = 16;    // samples per block
constexpr int BLOCK  = 256;
constexpr int DEPTH  = 8;
constexpr int NL     = 256;   // leaves
constexpr int IN_DIM = 128;
constexpr int EFF_IN = 130;
constexpr int HID    = 16;
constexpr int NC     = 10;

__global__ __launch_bounds__(BLOCK) void tree_fused(
    const float* __restrict__ x, const float* __restrict__ path_prob,
    const float* __restrict__ W1, const float* __restrict__ b1,
    const float* __restrict__ w2, const float* __restrict__ b2,
    const float* __restrict__ leaf_logits, float* __restrict__ out)
{
    __shared__ float xs[IN_DIM][TS + 1];   // +1 pad: conflict-free writes
    __shared__ float pp[NL][TS];           // strided path-prob slots
    __shared__ float sc[3][IN_DIM][TS];    // rotating score buffers (need d-1, d-2)
    __shared__ float ll[NL][NC];           // leaf logits

    const int tid = threadIdx.x;
    const int s0  = blockIdx.x * TS;

    // stage x tile transposed: xs[k][s]
    for (int i = tid; i < TS * IN_DIM; i += BLOCK) {
        int s = i >> 7, k = i & (IN_DIM - 1);
        xs[k][s] = x[(size_t)(s0 + s) * IN_DIM + k];
    }
    // stage leaf logits
    for (int i = tid; i < NL * NC; i += BLOCK)
        ll[i / NC][i % NC] = leaf_logits[i];
    // init pp: slot 0 = path_prob, rest are written before read
    for (int i = tid; i < NL * TS; i += BLOCK) {
        int slot = i / TS, s = i - slot * TS;
        pp[slot][s] = (slot == 0) ? path_prob[s0 + s] : 0.0f;
    }
    __syncthreads();

    for (int d = 0; d < DEPTH; ++d) {
        const int nd     = 1 << d;
        const int lo     = nd - 1;
        const int stride = NL >> d;        // pp slot stride at this depth
        const int half   = stride >> 1;
        float (*scNew)[TS]   = sc[d % 3];
        float (*scPrev)[TS]  = sc[(d + 2) % 3];   // depth d-1
        float (*scPrev2)[TS] = sc[(d + 1) % 3];   // depth d-2

        for (int task = tid; task < TS * nd; task += BLOCK) {
            const int s  = task & (TS - 1);
            const int nl = task >> 4;              // task / TS
            const int n  = lo + nl;
            const float* __restrict__ w = W1 + (size_t)n * (EFF_IN * HID);

            float4 h4[4];
            #pragma unroll
            for (int q = 0; q < 4; ++q) h4[q] = make_float4(0.f, 0.f, 0.f, 0.f);

            #pragma unroll 4
            for (int k = 0; k < IN_DIM; ++k) {
                const float xv = xs[k][s];
                const float4* __restrict__ wr = (const float4*)(w + k * HID);
                #pragma unroll
                for (int q = 0; q < 4; ++q) {
                    float4 wv = wr[q];
                    h4[q].x = fmaf(xv, wv.x, h4[q].x);
                    h4[q].y = fmaf(xv, wv.y, h4[q].y);
                    h4[q].z = fmaf(xv, wv.z, h4[q].z);
                    h4[q].w = fmaf(xv, wv.w, h4[q].w);
                }
            }

            const float parent = (d >= 1) ? scPrev[nl >> 1][s] : 0.0f;
            const float grandp = (d >= 2) ? scPrev2[nl >> 2][s] : 0.0f;
            const float4* __restrict__ wpar = (const float4*)(w + IN_DIM * HID);
            const float4* __restrict__ wgra = (const float4*)(w + (IN_DIM + 1) * HID);
            const float4* __restrict__ b1r  = (const float4*)(b1 + n * HID);
            const float4* __restrict__ w2r  = (const float4*)(w2 + n * HID);

            float score = b2[n];
            #pragma unroll
            for (int q = 0; q < 4; ++q) {
                const float4 hv = h4[q];
                const float4 wp = wpar[q];
                const float4 wg = wgra[q];
                const float4 bb = b1r[q];
                const float4 ww = w2r[q];
                float t;
                t = fmaxf(fmaf(parent, wp.x, fmaf(grandp, wg.x, hv.x + bb.x)), 0.f); score = fmaf(t, ww.x, score);
                t = fmaxf(fmaf(parent, wp.y, fmaf(grandp, wg.y, hv.y + bb.y)), 0.f); score = fmaf(t, ww.y, score);
                t = fmaxf(fmaf(parent, wp.z, fmaf(grandp, wg.z, hv.z + bb.z)), 0.f); score = fmaf(t, ww.z, score);
                t = fmaxf(fmaf(parent, wp.w, fmaf(grandp, wg.w, hv.w + bb.w)), 0.f); score = fmaf(t, ww.w, score);
            }

            const float p = 1.0f / (1.0f + __expf(-score));
            scNew[nl][s] = score;

            const int slot = nl * stride;
            const float ppar = pp[slot][s];
            pp[slot][s]        = ppar * p;
            pp[slot + half][s] = ppar * (1.0f - p);
        }
        __syncthreads();
    }

    // out[s][c] = sum_l pp[l][s] * ll[l][c]
    for (int t = tid; t < TS * NC; t += BLOCK) {
        const int s = t / NC, c = t - s * NC;
        float acc = 0.0f;
        for (int l = 0; l < NL; ++l)
            acc = fmaf(pp[l][s], ll[l][c], acc);
        out[(size_t)(s0 + s) * NC + c] = acc;
    }
}

} // namespace

extern "C" void kernel_launch(void* const* d_in, const int* in_sizes, int n_in,
                              void* d_out, int out_size, void* d_ws, size_t ws_size,
                              hipStream_t stream) {
    const float* x           = (const float*)d_in[0];
    const float* path_prob   = (const float*)d_in[1];
    const float* W1          = (const float*)d_in[2];
    const float* b1          = (const float*)d_in[3];
    const float* w2          = (const float*)d_in[4];
    const float* b2          = (const float*)d_in[5];
    const float* leaf_logits = (const float*)d_in[6];
    float* out = (float*)d_out;

    const int batch = in_sizes[0] / IN_DIM;   // 32768
    const int grid  = batch / TS;             // 2048 blocks

    hipLaunchKernelGGL(tree_fused, dim3(grid), dim3(BLOCK), 0, stream,
                       x, path_prob, W1, b1, w2, b2, leaf_logits, out);
}

// Round 2
// 374.803 us; speedup vs baseline: 5.4300x; 5.4300x over previous
//
#include <hip/hip_runtime.h>
#include <math.h>

namespace {

typedef __attribute__((ext_vector_type(8))) short bf16x8;
typedef __attribute__((ext_vector_type(4))) float f32x4;

constexpr int IN_DIM = 128;
constexpr int EFF    = 130 * 16;   // W1 node stride (floats)
constexpr int NODES  = 255;
constexpr int TS     = 32;         // samples per block (2 MFMA M-tiles)
constexpr int BLOCK  = 256;
constexpr int NC     = 10;

__device__ inline unsigned short f2bf(float f) {
    unsigned u = __float_as_uint(f);
    u += 0x7fff + ((u >> 16) & 1);          // RNE
    return (unsigned short)(u >> 16);
}
__device__ inline float bf2f(unsigned short h) {
    return __uint_as_float(((unsigned)h) << 16);
}

// ---- prep: W1[:, :128, :] -> MFMA B-fragment layout, bf16 hi/lo ----
// frag element (n, t, lane l, j): B[k = t*32 + (l>>4)*8 + j][hid = l&15]
__global__ __launch_bounds__(256) void prep_w1(const float* __restrict__ W1,
                                               unsigned short* __restrict__ bhi,
                                               unsigned short* __restrict__ blo) {
    int i = blockIdx.x * 256 + threadIdx.x;
    if (i >= NODES * 4 * 64) return;
    int l = i & 63, t = (i >> 6) & 3, n = i >> 8;
    int k0 = t * 32 + (l >> 4) * 8, hid = l & 15;
    const float* src = W1 + (size_t)n * EFF + hid;
    bf16x8 hv, lv;
    #pragma unroll
    for (int j = 0; j < 8; ++j) {
        float v = src[(size_t)(k0 + j) * 16];
        unsigned short h = f2bf(v);
        hv[j] = (short)h;
        lv[j] = (short)f2bf(v - bf2f(h));
    }
    ((bf16x8*)bhi)[i] = hv;
    ((bf16x8*)blo)[i] = lv;
}

// ---- main fused tree kernel (MFMA) ----
__global__ __launch_bounds__(BLOCK, 2) void tree_mfma(
    const float* __restrict__ x, const float* __restrict__ path_prob,
    const float* __restrict__ W1, const float* __restrict__ b1,
    const float* __restrict__ w2, const float* __restrict__ b2,
    const float* __restrict__ leaf_logits,
    const unsigned short* __restrict__ bhi, const unsigned short* __restrict__ blo,
    float* __restrict__ out)
{
    __shared__ float pp[256][TS];      // 32 KB path-prob slots (strided scheme)
    __shared__ float sc[3][64][TS];    // 24 KB rotating score buffers (d-1, d-2)

    const int tid  = threadIdx.x;
    const int wv   = tid >> 6, l = tid & 63;
    const int quad = l >> 4,   hid = l & 15;
    const int s0   = blockIdx.x * TS;

    if (tid < TS) pp[0][tid] = path_prob[s0 + tid];

    // A fragments (x tile, hi/lo) straight from global into VGPRs; reused for all 255 nodes.
    // A[m = lane&15 (+16*mt)][k = t*32 + quad*8 + j]
    bf16x8 ah[4][2], al[4][2];
    #pragma unroll
    for (int t = 0; t < 4; ++t)
        #pragma unroll
        for (int mt = 0; mt < 2; ++mt) {
            const int m = mt * 16 + hid;
            const float* xp = x + (size_t)(s0 + m) * IN_DIM + t * 32 + quad * 8;
            float4 v0 = ((const float4*)xp)[0];
            float4 v1 = ((const float4*)xp)[1];
            float vv[8] = {v0.x, v0.y, v0.z, v0.w, v1.x, v1.y, v1.z, v1.w};
            bf16x8 hv, lv;
            #pragma unroll
            for (int j = 0; j < 8; ++j) {
                unsigned short h = f2bf(vv[j]);
                hv[j] = (short)h;
                lv[j] = (short)f2bf(vv[j] - bf2f(h));
            }
            ah[t][mt] = hv; al[t][mt] = lv;
        }
    __syncthreads();

    const bf16x8* Bh = (const bf16x8*)bhi;
    const bf16x8* Bl = (const bf16x8*)blo;

    for (int d = 0; d < 8; ++d) {
        const int nd = 1 << d;
        float (*scW)[TS]  = sc[d % 3];
        float (*scP)[TS]  = sc[(d + 2) % 3];   // depth d-1 scores
        float (*scP2)[TS] = sc[(d + 1) % 3];   // depth d-2 scores
        const int stride = 256 >> d, half = 128 >> d;

        for (int nl = wv; nl < nd; nl += 4) {
            const int n = nd - 1 + nl;

            // coalesced B fragments (hi/lo), L2-resident
            bf16x8 bh[4], bl_[4];
            #pragma unroll
            for (int t = 0; t < 4; ++t) {
                bh[t]  = Bh[(n * 4 + t) * 64 + l];
                bl_[t] = Bl[(n * 4 + t) * 64 + l];
            }
            // per-node scalars — issued early, consumed after the MFMAs
            const float b1v = b1[n * 16 + hid];
            const float w2v = w2[n * 16 + hid];
            const float b2v = b2[n];
            const float wpv = W1[(size_t)n * EFF + 128 * 16 + hid];
            const float wgv = W1[(size_t)n * EFF + 129 * 16 + hid];

            f32x4 acc0 = {0.f, 0.f, 0.f, 0.f}, acc1 = {0.f, 0.f, 0.f, 0.f};
            #pragma unroll
            for (int t = 0; t < 4; ++t) {
                acc0 = __builtin_amdgcn_mfma_f32_16x16x32_bf16(ah[t][0], bh[t],  acc0, 0, 0, 0);
                acc1 = __builtin_amdgcn_mfma_f32_16x16x32_bf16(ah[t][1], bh[t],  acc1, 0, 0, 0);
                acc0 = __builtin_amdgcn_mfma_f32_16x16x32_bf16(ah[t][0], bl_[t], acc0, 0, 0, 0);
                acc1 = __builtin_amdgcn_mfma_f32_16x16x32_bf16(ah[t][1], bl_[t], acc1, 0, 0, 0);
                acc0 = __builtin_amdgcn_mfma_f32_16x16x32_bf16(al[t][0], bh[t],  acc0, 0, 0, 0);
                acc1 = __builtin_amdgcn_mfma_f32_16x16x32_bf16(al[t][1], bh[t],  acc1, 0, 0, 0);
            }

            // epilogue: relu(h + b1 + par*wp + gp*wg) . w2  -> score per sample
            // C layout: col(hid)=lane&15, row(s)=quad*4+reg
            float score[2][4];
            #pragma unroll
            for (int mt = 0; mt < 2; ++mt) {
                const f32x4 a = mt ? acc1 : acc0;
                #pragma unroll
                for (int r = 0; r < 4; ++r) {
                    const int s = mt * 16 + quad * 4 + r;
                    const float par = (d >= 1) ? scP[nl >> 1][s] : 0.0f;
                    const float gp  = (d >= 2) ? scP2[nl >> 2][s] : 0.0f;
                    float h = a[r] + b1v + par * wpv + gp * wgv;
                    float tt = fmaxf(h, 0.0f) * w2v;
                    tt += __shfl_xor(tt, 1);
                    tt += __shfl_xor(tt, 2);
                    tt += __shfl_xor(tt, 4);
                    tt += __shfl_xor(tt, 8);
                    score[mt][r] = tt + b2v;
                }
            }
            if (d < 7 && hid == 0) {
                #pragma unroll
                for (int mt = 0; mt < 2; ++mt)
                    #pragma unroll
                    for (int r = 0; r < 4; ++r)
                        scW[nl][mt * 16 + quad * 4 + r] = score[mt][r];
            }
            if (hid < 4) {
                #pragma unroll
                for (int mt = 0; mt < 2; ++mt) {
                    const int s = mt * 16 + quad * 4 + hid;
                    const float sv = score[mt][hid];
                    const float p = 1.0f / (1.0f + __expf(-sv));
                    const int slot = nl * stride;
                    const float ppar = pp[slot][s];
                    pp[slot][s]        = ppar * p;
                    pp[slot + half][s] = ppar * (1.0f - p);
                }
            }
        }
        __syncthreads();
    }

    // leaf mixture: out[s][c] = sum_l pp[l][s] * ll[l][c]; stage ll into dead sc space
    float* llb = &sc[0][0][0];                       // 2560 floats <= 6144
    for (int i = tid; i < 256 * NC; i += BLOCK) llb[i] = leaf_logits[i];
    __syncthreads();
    for (int i = tid; i < TS * NC; i += BLOCK) {
        const int s = i / NC, c = i - s * NC;
        float acc = 0.0f;
        for (int lf = 0; lf < 256; ++lf)
            acc = fmaf(pp[lf][s], llb[lf * NC + c], acc);
        out[(size_t)(s0 + s) * NC + c] = acc;
    }
}

// ---- round-1 fallback (used only if d_ws is too small) ----
__global__ __launch_bounds__(BLOCK) void tree_fused(
    const float* __restrict__ x, const float* __restrict__ path_prob,
    const float* __restrict__ W1, const float* __restrict__ b1,
    const float* __restrict__ w2, const float* __restrict__ b2,
    const float* __restrict__ leaf_logits, float* __restrict__ out)
{
    constexpr int FTS = 16;
    __shared__ float xs[IN_DIM][FTS + 1];
    __shared__ float pp[256][FTS];
    __shared__ float sc[3][IN_DIM][FTS];
    __shared__ float ll[256][NC];

    const int tid = threadIdx.x;
    const int s0  = blockIdx.x * FTS;

    for (int i = tid; i < FTS * IN_DIM; i += BLOCK) {
        int s = i >> 7, k = i & (IN_DIM - 1);
        xs[k][s] = x[(size_t)(s0 + s) * IN_DIM + k];
    }
    for (int i = tid; i < 256 * NC; i += BLOCK)
        ll[i / NC][i % NC] = leaf_logits[i];
    for (int i = tid; i < 256 * FTS; i += BLOCK) {
        int slot = i / FTS, s = i - slot * FTS;
        pp[slot][s] = (slot == 0) ? path_prob[s0 + s] : 0.0f;
    }
    __syncthreads();

    for (int d = 0; d < 8; ++d) {
        const int nd = 1 << d;
        const int lo = nd - 1;
        const int stride = 256 >> d;
        const int half = stride >> 1;
        float (*scNew)[FTS]   = sc[d % 3];
        float (*scPrev)[FTS]  = sc[(d + 2) % 3];
        float (*scPrev2)[FTS] = sc[(d + 1) % 3];

        for (int task = tid; task < FTS * nd; task += BLOCK) {
            const int s  = task & (FTS - 1);
            const int nl = task >> 4;
            const int n  = lo + nl;
            const float* __restrict__ w = W1 + (size_t)n * EFF;

            float4 h4[4];
            #pragma unroll
            for (int q = 0; q < 4; ++q) h4[q] = make_float4(0.f, 0.f, 0.f, 0.f);

            #pragma unroll 4
            for (int k = 0; k < IN_DIM; ++k) {
                const float xv = xs[k][s];
                const float4* __restrict__ wr = (const float4*)(w + k * 16);
                #pragma unroll
                for (int q = 0; q < 4; ++q) {
                    float4 wvv = wr[q];
                    h4[q].x = fmaf(xv, wvv.x, h4[q].x);
                    h4[q].y = fmaf(xv, wvv.y, h4[q].y);
                    h4[q].z = fmaf(xv, wvv.z, h4[q].z);
                    h4[q].w = fmaf(xv, wvv.w, h4[q].w);
                }
            }

            const float parent = (d >= 1) ? scPrev[nl >> 1][s] : 0.0f;
            const float grandp = (d >= 2) ? scPrev2[nl >> 2][s] : 0.0f;
            const float4* __restrict__ wpar = (const float4*)(w + 128 * 16);
            const float4* __restrict__ wgra = (const float4*)(w + 129 * 16);
            const float4* __restrict__ b1r  = (const float4*)(b1 + n * 16);
            const float4* __restrict__ w2r  = (const float4*)(w2 + n * 16);

            float score = b2[n];
            #pragma unroll
            for (int q = 0; q < 4; ++q) {
                const float4 hv = h4[q];
                const float4 wp = wpar[q];
                const float4 wg = wgra[q];
                const float4 bb = b1r[q];
                const float4 ww = w2r[q];
                float t;
                t = fmaxf(fmaf(parent, wp.x, fmaf(grandp, wg.x, hv.x + bb.x)), 0.f); score = fmaf(t, ww.x, score);
                t = fmaxf(fmaf(parent, wp.y, fmaf(grandp, wg.y, hv.y + bb.y)), 0.f); score = fmaf(t, ww.y, score);
                t = fmaxf(fmaf(parent, wp.z, fmaf(grandp, wg.z, hv.z + bb.z)), 0.f); score = fmaf(t, ww.z, score);
                t = fmaxf(fmaf(parent, wp.w, fmaf(grandp, wg.w, hv.w + bb.w)), 0.f); score = fmaf(t, ww.w, score);
            }

            const float p = 1.0f / (1.0f + __expf(-score));
            scNew[nl][s] = score;

            const int slot = nl * stride;
            const float ppar = pp[slot][s];
            pp[slot][s]        = ppar * p;
            pp[slot + half][s] = ppar * (1.0f - p);
        }
        __syncthreads();
    }

    for (int t = tid; t < FTS * NC; t += BLOCK) {
        const int s = t / NC, c = t - s * NC;
        float acc = 0.0f;
        for (int lf = 0; lf < 256; ++lf)
            acc = fmaf(pp[lf][s], ll[lf][c], acc);
        out[(size_t)(s0 + s) * NC + c] = acc;
    }
}

} // namespace

extern "C" void kernel_launch(void* const* d_in, const int* in_sizes, int n_in,
                              void* d_out, int out_size, void* d_ws, size_t ws_size,
                              hipStream_t stream) {
    const float* x           = (const float*)d_in[0];
    const float* path_prob   = (const float*)d_in[1];
    const float* W1          = (const float*)d_in[2];
    const float* b1          = (const float*)d_in[3];
    const float* w2          = (const float*)d_in[4];
    const float* b2          = (const float*)d_in[5];
    const float* leaf_logits = (const float*)d_in[6];
    float* out = (float*)d_out;

    const int batch = in_sizes[0] / IN_DIM;           // 32768
    const size_t fragElems = (size_t)NODES * 4 * 64 * 8;   // per precision
    const size_t wsNeed = fragElems * 2 * 2;               // hi+lo, 2 B each

    if (ws_size >= wsNeed) {
        unsigned short* bhi = (unsigned short*)d_ws;
        unsigned short* blo = bhi + fragElems;
        hipLaunchKernelGGL(prep_w1, dim3((NODES * 4 * 64 + 255) / 256), dim3(256), 0, stream,
                           W1, bhi, blo);
        hipLaunchKernelGGL(tree_mfma, dim3(batch / TS), dim3(BLOCK), 0, stream,
                           x, path_prob, W1, b1, w2, b2, leaf_logits, bhi, blo, out);
    } else {
        hipLaunchKernelGGL(tree_fused, dim3(batch / 16), dim3(BLOCK), 0, stream,
                           x, path_prob, W1, b1, w2, b2, leaf_logits, out);
    }
}

// Round 3
// 239.223 us; speedup vs baseline: 8.5075x; 1.5668x over previous
//
#include <hip/hip_runtime.h>
#include <math.h>

namespace {

typedef __attribute__((ext_vector_type(8))) short bf16x8;
typedef __attribute__((ext_vector_type(4))) float f32x4;

constexpr int IN_DIM = 128;
constexpr int EFF    = 130 * 16;   // W1 node stride (floats)
constexpr int NODES  = 255;
constexpr int TS     = 32;         // samples per block (2 MFMA N-tiles)
constexpr int BLOCK  = 256;
constexpr int NC     = 10;

__device__ inline unsigned short f2bf(float f) {
    unsigned u = __float_as_uint(f);
    u += 0x7fff + ((u >> 16) & 1);          // RNE
    return (unsigned short)(u >> 16);
}
__device__ inline float bf2f(unsigned short h) {
    return __uint_as_float(((unsigned)h) << 16);
}

// ---- prep: W1[:, :128, :] -> MFMA fragment layout, bf16 hi/lo ----
// One block per node; coalesced float4 global reads via LDS staging.
// frag element (n, t, lane l, j): W[k = t*32 + (l>>4)*8 + j][hid = l&15]
__global__ __launch_bounds__(256) void prep_w1(const float* __restrict__ W1,
                                               unsigned short* __restrict__ bhi,
                                               unsigned short* __restrict__ blo) {
    __shared__ float xs[IN_DIM * 16];      // 8 KB: rows 0..127 of this node
    const int n = blockIdx.x, tid = threadIdx.x;
    const float4* src = (const float4*)(W1 + (size_t)n * EFF);
    ((float4*)xs)[tid]       = src[tid];
    ((float4*)xs)[tid + 256] = src[tid + 256];
    __syncthreads();
    const int l = tid & 63, t = tid >> 6;
    const int k0 = t * 32 + (l >> 4) * 8, hid = l & 15;
    bf16x8 hv, lv;
    #pragma unroll
    for (int j = 0; j < 8; ++j) {
        float v = xs[(k0 + j) * 16 + hid];
        unsigned short h = f2bf(v);
        hv[j] = (short)h;
        lv[j] = (short)f2bf(v - bf2f(h));
    }
    ((bf16x8*)bhi)[(n * 4 + t) * 64 + l] = hv;
    ((bf16x8*)blo)[(n * 4 + t) * 64 + l] = lv;
}

// ---- main fused tree kernel (transposed MFMA: D[hid][s]) ----
__global__ __launch_bounds__(BLOCK, 3) void tree_mfma(
    const float* __restrict__ x, const float* __restrict__ path_prob,
    const float* __restrict__ W1, const float* __restrict__ b1,
    const float* __restrict__ w2, const float* __restrict__ b2,
    const float* __restrict__ leaf_logits,
    const unsigned short* __restrict__ bhi, const unsigned short* __restrict__ blo,
    float* __restrict__ out)
{
    __shared__ float pp[256][TS];          // 32 KB path-prob slots (strided scheme)
    // exact-sized rotating score buffers: written at depth d -> buf d%3
    // buf0 (d=0,3,6): 64 rows @0; buf1 (d=1,4): 16 rows @64; buf2 (d=2,5): 32 rows @80
    __shared__ float scbuf[112][TS];       // 14 KB

    const int tid  = threadIdx.x;
    const int wv   = tid >> 6, l = tid & 63;
    const int quad = l >> 4,   col = l & 15;
    const int s0   = blockIdx.x * TS;

    if (tid < TS) pp[0][tid] = path_prob[s0 + tid];

    // x fragments (hi/lo) -> B operand: B[k = t*32+quad*8+j][col = sample&15]
    bf16x8 xh[4][2], xl[4][2];
    #pragma unroll
    for (int t = 0; t < 4; ++t)
        #pragma unroll
        for (int mt = 0; mt < 2; ++mt) {
            const float* xp = x + (size_t)(s0 + mt * 16 + col) * IN_DIM + t * 32 + quad * 8;
            float4 v0 = ((const float4*)xp)[0];
            float4 v1 = ((const float4*)xp)[1];
            float vv[8] = {v0.x, v0.y, v0.z, v0.w, v1.x, v1.y, v1.z, v1.w};
            bf16x8 hv, lv;
            #pragma unroll
            for (int j = 0; j < 8; ++j) {
                unsigned short h = f2bf(vv[j]);
                hv[j] = (short)h;
                lv[j] = (short)f2bf(vv[j] - bf2f(h));
            }
            xh[t][mt] = hv; xl[t][mt] = lv;
        }
    __syncthreads();

    const bf16x8* Wh = (const bf16x8*)bhi;
    const bf16x8* Wl = (const bf16x8*)blo;
    const int wbase[3] = {0, 64, 80};

    for (int d = 0; d < 8; ++d) {
        const int nd = 1 << d;
        float (*scW)[TS]  = (float(*)[TS])&scbuf[wbase[d % 3]][0];
        float (*scP)[TS]  = (float(*)[TS])&scbuf[wbase[(d + 2) % 3]][0];   // d-1
        float (*scP2)[TS] = (float(*)[TS])&scbuf[wbase[(d + 1) % 3]][0];   // d-2
        const int stride = 256 >> d, half = 128 >> d;

        for (int nl = wv; nl < nd; nl += 4) {
            const int n = nd - 1 + nl;

            // W fragments (hi/lo) -> A operand: A[m = hid][k]; L2-resident, coalesced
            bf16x8 wh[4], wl_[4];
            #pragma unroll
            for (int t = 0; t < 4; ++t) {
                wh[t]  = Wh[(n * 4 + t) * 64 + l];
                wl_[t] = Wl[(n * 4 + t) * 64 + l];
            }
            // per-node row vectors along hid (this lane's rows: quad*4 + r)
            const float4 b1q = ((const float4*)(b1 + n * 16))[quad];
            const float4 w2q = ((const float4*)(w2 + n * 16))[quad];
            const float4 wpq = ((const float4*)(W1 + (size_t)n * EFF + 128 * 16))[quad];
            const float4 wgq = ((const float4*)(W1 + (size_t)n * EFF + 129 * 16))[quad];
            const float  b2v = b2[n];

            f32x4 acc0 = {0.f, 0.f, 0.f, 0.f}, acc1 = {0.f, 0.f, 0.f, 0.f};
            #pragma unroll
            for (int t = 0; t < 4; ++t) {
                acc0 = __builtin_amdgcn_mfma_f32_16x16x32_bf16(wh[t],  xh[t][0], acc0, 0, 0, 0);
                acc1 = __builtin_amdgcn_mfma_f32_16x16x32_bf16(wh[t],  xh[t][1], acc1, 0, 0, 0);
                acc0 = __builtin_amdgcn_mfma_f32_16x16x32_bf16(wl_[t], xh[t][0], acc0, 0, 0, 0);
                acc1 = __builtin_amdgcn_mfma_f32_16x16x32_bf16(wl_[t], xh[t][1], acc1, 0, 0, 0);
                acc0 = __builtin_amdgcn_mfma_f32_16x16x32_bf16(wh[t],  xl[t][0], acc0, 0, 0, 0);
                acc1 = __builtin_amdgcn_mfma_f32_16x16x32_bf16(wh[t],  xl[t][1], acc1, 0, 0, 0);
            }

            // epilogue: D[hid=quad*4+r][s=col]; reduce over hid = 3 in-lane adds + 2 shfls
            float score01[2];
            #pragma unroll
            for (int mt = 0; mt < 2; ++mt) {
                const f32x4 a = mt ? acc1 : acc0;
                const int scol = mt * 16 + col;
                const float par = (d >= 1) ? scP[nl >> 1][scol] : 0.0f;
                const float gp  = (d >= 2) ? scP2[nl >> 2][scol] : 0.0f;
                float ts = 0.0f;
                #pragma unroll
                for (int r = 0; r < 4; ++r) {
                    const float brr = (r == 0) ? b1q.x : (r == 1) ? b1q.y : (r == 2) ? b1q.z : b1q.w;
                    const float wpr = (r == 0) ? wpq.x : (r == 1) ? wpq.y : (r == 2) ? wpq.z : wpq.w;
                    const float wgr = (r == 0) ? wgq.x : (r == 1) ? wgq.y : (r == 2) ? wgq.z : wgq.w;
                    const float w2r = (r == 0) ? w2q.x : (r == 1) ? w2q.y : (r == 2) ? w2q.z : w2q.w;
                    const float h = a[r] + brr + par * wpr + gp * wgr;
                    ts = fmaf(fmaxf(h, 0.0f), w2r, ts);
                }
                ts += __shfl_xor(ts, 16);
                ts += __shfl_xor(ts, 32);
                score01[mt] = ts + b2v;
            }
            if (l < 32) {
                const int s = l;
                const float sv = (l < 16) ? score01[0] : score01[1];
                if (d < 7) scW[nl][s] = sv;
                const float p = 1.0f / (1.0f + __expf(-sv));
                const int slot = nl * stride;
                const float ppar = pp[slot][s];
                pp[slot][s]        = ppar * p;
                pp[slot + half][s] = ppar * (1.0f - p);
            }
        }
        __syncthreads();
    }

    // leaf mixture: out[s][c] = sum_l pp[l][s] * ll[l][c]; stage ll into dead scbuf space
    float* llb = &scbuf[0][0];                       // 2560 floats <= 3584
    for (int i = tid; i < 256 * NC; i += BLOCK) llb[i] = leaf_logits[i];
    __syncthreads();
    for (int i = tid; i < TS * NC; i += BLOCK) {
        const int s = i / NC, c = i - s * NC;
        float acc = 0.0f;
        for (int lf = 0; lf < 256; ++lf)
            acc = fmaf(pp[lf][s], llb[lf * NC + c], acc);
        out[(size_t)(s0 + s) * NC + c] = acc;
    }
}

// ---- round-1 fallback (used only if d_ws is too small) ----
__global__ __launch_bounds__(BLOCK) void tree_fused(
    const float* __restrict__ x, const float* __restrict__ path_prob,
    const float* __restrict__ W1, const float* __restrict__ b1,
    const float* __restrict__ w2, const float* __restrict__ b2,
    const float* __restrict__ leaf_logits, float* __restrict__ out)
{
    constexpr int FTS = 16;
    __shared__ float xs[IN_DIM][FTS + 1];
    __shared__ float pp[256][FTS];
    __shared__ float sc[3][IN_DIM][FTS];
    __shared__ float ll[256][NC];

    const int tid = threadIdx.x;
    const int s0  = blockIdx.x * FTS;

    for (int i = tid; i < FTS * IN_DIM; i += BLOCK) {
        int s = i >> 7, k = i & (IN_DIM - 1);
        xs[k][s] = x[(size_t)(s0 + s) * IN_DIM + k];
    }
    for (int i = tid; i < 256 * NC; i += BLOCK)
        ll[i / NC][i % NC] = leaf_logits[i];
    for (int i = tid; i < 256 * FTS; i += BLOCK) {
        int slot = i / FTS, s = i - slot * FTS;
        pp[slot][s] = (slot == 0) ? path_prob[s0 + s] : 0.0f;
    }
    __syncthreads();

    for (int d = 0; d < 8; ++d) {
        const int nd = 1 << d;
        const int lo = nd - 1;
        const int stride = 256 >> d;
        const int half = stride >> 1;
        float (*scNew)[FTS]   = sc[d % 3];
        float (*scPrev)[FTS]  = sc[(d + 2) % 3];
        float (*scPrev2)[FTS] = sc[(d + 1) % 3];

        for (int task = tid; task < FTS * nd; task += BLOCK) {
            const int s  = task & (FTS - 1);
            const int nl = task >> 4;
            const int n  = lo + nl;
            const float* __restrict__ w = W1 + (size_t)n * EFF;

            float4 h4[4];
            #pragma unroll
            for (int q = 0; q < 4; ++q) h4[q] = make_float4(0.f, 0.f, 0.f, 0.f);

            #pragma unroll 4
            for (int k = 0; k < IN_DIM; ++k) {
                const float xv = xs[k][s];
                const float4* __restrict__ wr = (const float4*)(w + k * 16);
                #pragma unroll
                for (int q = 0; q < 4; ++q) {
                    float4 wvv = wr[q];
                    h4[q].x = fmaf(xv, wvv.x, h4[q].x);
                    h4[q].y = fmaf(xv, wvv.y, h4[q].y);
                    h4[q].z = fmaf(xv, wvv.z, h4[q].z);
                    h4[q].w = fmaf(xv, wvv.w, h4[q].w);
                }
            }

            const float parent = (d >= 1) ? scPrev[nl >> 1][s] : 0.0f;
            const float grandp = (d >= 2) ? scPrev2[nl >> 2][s] : 0.0f;
            const float4* __restrict__ wpar = (const float4*)(w + 128 * 16);
            const float4* __restrict__ wgra = (const float4*)(w + 129 * 16);
            const float4* __restrict__ b1r  = (const float4*)(b1 + n * 16);
            const float4* __restrict__ w2r  = (const float4*)(w2 + n * 16);

            float score = b2[n];
            #pragma unroll
            for (int q = 0; q < 4; ++q) {
                const float4 hv = h4[q];
                const float4 wp = wpar[q];
                const float4 wg = wgra[q];
                const float4 bb = b1r[q];
                const float4 ww = w2r[q];
                float t;
                t = fmaxf(fmaf(parent, wp.x, fmaf(grandp, wg.x, hv.x + bb.x)), 0.f); score = fmaf(t, ww.x, score);
                t = fmaxf(fmaf(parent, wp.y, fmaf(grandp, wg.y, hv.y + bb.y)), 0.f); score = fmaf(t, ww.y, score);
                t = fmaxf(fmaf(parent, wp.z, fmaf(grandp, wg.z, hv.z + bb.z)), 0.f); score = fmaf(t, ww.z, score);
                t = fmaxf(fmaf(parent, wp.w, fmaf(grandp, wg.w, hv.w + bb.w)), 0.f); score = fmaf(t, ww.w, score);
            }

            const float p = 1.0f / (1.0f + __expf(-score));
            scNew[nl][s] = score;

            const int slot = nl * stride;
            const float ppar = pp[slot][s];
            pp[slot][s]        = ppar * p;
            pp[slot + half][s] = ppar * (1.0f - p);
        }
        __syncthreads();
    }

    for (int t = tid; t < FTS * NC; t += BLOCK) {
        const int s = t / NC, c = t - s * NC;
        float acc = 0.0f;
        for (int lf = 0; lf < 256; ++lf)
            acc = fmaf(pp[lf][s], ll[lf][c], acc);
        out[(size_t)(s0 + s) * NC + c] = acc;
    }
}

} // namespace

extern "C" void kernel_launch(void* const* d_in, const int* in_sizes, int n_in,
                              void* d_out, int out_size, void* d_ws, size_t ws_size,
                              hipStream_t stream) {
    const float* x           = (const float*)d_in[0];
    const float* path_prob   = (const float*)d_in[1];
    const float* W1          = (const float*)d_in[2];
    const float* b1          = (const float*)d_in[3];
    const float* w2          = (const float*)d_in[4];
    const float* b2          = (const float*)d_in[5];
    const float* leaf_logits = (const float*)d_in[6];
    float* out = (float*)d_out;

    const int batch = in_sizes[0] / IN_DIM;                // 32768
    const size_t fragElems = (size_t)NODES * 4 * 64 * 8;   // per precision
    const size_t wsNeed = fragElems * 2 * 2;               // hi+lo, 2 B each

    if (ws_size >= wsNeed) {
        unsigned short* bhi = (unsigned short*)d_ws;
        unsigned short* blo = bhi + fragElems;
        hipLaunchKernelGGL(prep_w1, dim3(NODES), dim3(256), 0, stream, W1, bhi, blo);
        hipLaunchKernelGGL(tree_mfma, dim3(batch / TS), dim3(BLOCK), 0, stream,
                           x, path_prob, W1, b1, w2, b2, leaf_logits, bhi, blo, out);
    } else {
        hipLaunchKernelGGL(tree_fused, dim3(batch / 16), dim3(BLOCK), 0, stream,
                           x, path_prob, W1, b1, w2, b2, leaf_logits, out);
    }
}

// Round 4
// 204.481 us; speedup vs baseline: 9.9529x; 1.1699x over previous
//
#include <hip/hip_runtime.h>
#include <math.h>

namespace {

typedef __attribute__((ext_vector_type(8))) short bf16x8;
typedef __attribute__((ext_vector_type(4))) float f32x4;

constexpr int IN_DIM = 128;
constexpr int EFF    = 130 * 16;   // W1 node stride (floats)
constexpr int NODES  = 255;
constexpr int TS     = 64;         // samples per block (4 MFMA N-tiles per wave)
constexpr int BLOCK  = 256;
constexpr int NC     = 10;

__device__ inline unsigned short f2bf(float f) {
    unsigned u = __float_as_uint(f);
    u += 0x7fff + ((u >> 16) & 1);          // RNE
    return (unsigned short)(u >> 16);
}
__device__ inline float bf2f(unsigned short h) {
    return __uint_as_float(((unsigned)h) << 16);
}

// ---- prep: W1[:, :128, :] -> MFMA fragment layout, bf16 hi/lo ----
// One block per node; coalesced float4 global reads via LDS staging.
// frag element (n, t, lane l, j): W[k = t*32 + (l>>4)*8 + j][hid = l&15]
__global__ __launch_bounds__(256) void prep_w1(const float* __restrict__ W1,
                                               unsigned short* __restrict__ bhi,
                                               unsigned short* __restrict__ blo) {
    __shared__ float xs[IN_DIM * 16];      // 8 KB: rows 0..127 of this node
    const int n = blockIdx.x, tid = threadIdx.x;
    const float4* src = (const float4*)(W1 + (size_t)n * EFF);
    ((float4*)xs)[tid]       = src[tid];
    ((float4*)xs)[tid + 256] = src[tid + 256];
    __syncthreads();
    const int l = tid & 63, t = tid >> 6;
    const int k0 = t * 32 + (l >> 4) * 8, hid = l & 15;
    bf16x8 hv, lv;
    #pragma unroll
    for (int j = 0; j < 8; ++j) {
        float v = xs[(k0 + j) * 16 + hid];
        unsigned short h = f2bf(v);
        hv[j] = (short)h;
        lv[j] = (short)f2bf(v - bf2f(h));
    }
    ((bf16x8*)bhi)[(n * 4 + t) * 64 + l] = hv;
    ((bf16x8*)blo)[(n * 4 + t) * 64 + l] = lv;
}

// ---- main fused tree kernel (transposed MFMA D[hid][s], TS=64, leaf-fold) ----
__global__ __launch_bounds__(BLOCK, 2) void tree_mfma(
    const float* __restrict__ x, const float* __restrict__ path_prob,
    const float* __restrict__ W1, const float* __restrict__ b1,
    const float* __restrict__ w2, const float* __restrict__ b2,
    const float* __restrict__ leaf_logits,
    const unsigned short* __restrict__ bhi, const unsigned short* __restrict__ blo,
    float* __restrict__ out)
{
    __shared__ float pp[128][TS];          // 32 KB: path probs, depths 0..6 only
    // exact-sized rotating score buffers: written at depth d -> buf d%3
    // buf0 (d=0,3,6): 64 rows @0; buf1 (d=1,4): 16 rows @64; buf2 (d=2,5): 32 rows @80
    __shared__ float scbuf[112][TS];       // 28 KB (reused for out-reduction)

    const int tid  = threadIdx.x;
    const int wv   = tid >> 6, l = tid & 63;
    const int quad = l >> 4,   col = l & 15;
    const int s0   = blockIdx.x * TS;

    if (tid < TS) pp[0][tid] = path_prob[s0 + tid];

    // x fragments (hi/lo) -> B operand: B[k = t*32+quad*8+j][col = sample&15]
    bf16x8 xh[4][4], xl[4][4];
    #pragma unroll
    for (int t = 0; t < 4; ++t)
        #pragma unroll
        for (int mt = 0; mt < 4; ++mt) {
            const float* xp = x + (size_t)(s0 + mt * 16 + col) * IN_DIM + t * 32 + quad * 8;
            float4 v0 = ((const float4*)xp)[0];
            float4 v1 = ((const float4*)xp)[1];
            float vv[8] = {v0.x, v0.y, v0.z, v0.w, v1.x, v1.y, v1.z, v1.w};
            bf16x8 hv, lv;
            #pragma unroll
            for (int j = 0; j < 8; ++j) {
                unsigned short h = f2bf(vv[j]);
                hv[j] = (short)h;
                lv[j] = (short)f2bf(vv[j] - bf2f(h));
            }
            xh[t][mt] = hv; xl[t][mt] = lv;
        }
    __syncthreads();

    const bf16x8* Wh = (const bf16x8*)bhi;
    const bf16x8* Wl = (const bf16x8*)blo;
    const int wbase[3] = {0, 64, 80};

    float oacc[NC];
    #pragma unroll
    for (int c = 0; c < NC; ++c) oacc[c] = 0.0f;

    // ---------------- depths 0..6 ----------------
    for (int d = 0; d < 7; ++d) {
        const int nd = 1 << d;
        float (*scW)[TS]  = (float(*)[TS])&scbuf[wbase[d % 3]][0];
        float (*scP)[TS]  = (float(*)[TS])&scbuf[wbase[(d + 2) % 3]][0];   // d-1
        float (*scP2)[TS] = (float(*)[TS])&scbuf[wbase[(d + 1) % 3]][0];   // d-2
        const int stride = 128 >> d, half = 64 >> d;

        for (int nl = wv; nl < nd; nl += 4) {
            const int n = nd - 1 + nl;

            bf16x8 wh[4], wl_[4];
            #pragma unroll
            for (int t = 0; t < 4; ++t) {
                wh[t]  = Wh[(n * 4 + t) * 64 + l];
                wl_[t] = Wl[(n * 4 + t) * 64 + l];
            }
            const float4 b1q = ((const float4*)(b1 + n * 16))[quad];
            const float4 w2q = ((const float4*)(w2 + n * 16))[quad];
            const float4 wpq = ((const float4*)(W1 + (size_t)n * EFF + 128 * 16))[quad];
            const float4 wgq = ((const float4*)(W1 + (size_t)n * EFF + 129 * 16))[quad];
            const float  b2v = b2[n];

            f32x4 acc[4] = {{0.f,0.f,0.f,0.f},{0.f,0.f,0.f,0.f},{0.f,0.f,0.f,0.f},{0.f,0.f,0.f,0.f}};
            #pragma unroll
            for (int t = 0; t < 4; ++t) {
                #pragma unroll
                for (int mt = 0; mt < 4; ++mt)
                    acc[mt] = __builtin_amdgcn_mfma_f32_16x16x32_bf16(wh[t],  xh[t][mt], acc[mt], 0, 0, 0);
                #pragma unroll
                for (int mt = 0; mt < 4; ++mt)
                    acc[mt] = __builtin_amdgcn_mfma_f32_16x16x32_bf16(wl_[t], xh[t][mt], acc[mt], 0, 0, 0);
                #pragma unroll
                for (int mt = 0; mt < 4; ++mt)
                    acc[mt] = __builtin_amdgcn_mfma_f32_16x16x32_bf16(wh[t],  xl[t][mt], acc[mt], 0, 0, 0);
            }

            // epilogue: D[hid=quad*4+r][s=mt*16+col]; hid-reduce = 3 in-lane adds + 2 shfls
            float score01[4];
            #pragma unroll
            for (int mt = 0; mt < 4; ++mt) {
                const int scol = mt * 16 + col;
                const float par = (d >= 1) ? scP[nl >> 1][scol] : 0.0f;
                const float gp  = (d >= 2) ? scP2[nl >> 2][scol] : 0.0f;
                const f32x4 a = acc[mt];
                float ts = 0.0f;
                #pragma unroll
                for (int r = 0; r < 4; ++r) {
                    const float brr = (r == 0) ? b1q.x : (r == 1) ? b1q.y : (r == 2) ? b1q.z : b1q.w;
                    const float wpr = (r == 0) ? wpq.x : (r == 1) ? wpq.y : (r == 2) ? wpq.z : wpq.w;
                    const float wgr = (r == 0) ? wgq.x : (r == 1) ? wgq.y : (r == 2) ? wgq.z : wgq.w;
                    const float w2r = (r == 0) ? w2q.x : (r == 1) ? w2q.y : (r == 2) ? w2q.z : w2q.w;
                    const float h = a[r] + brr + par * wpr + gp * wgr;
                    ts = fmaf(fmaxf(h, 0.0f), w2r, ts);
                }
                ts += __shfl_xor(ts, 16);
                ts += __shfl_xor(ts, 32);
                score01[mt] = ts;
            }
            // lane l owns sample l: select its score
            const float sa = (quad & 1) ? score01[1] : score01[0];
            const float sb = (quad & 1) ? score01[3] : score01[2];
            const float sv = ((quad & 2) ? sb : sa) + b2v;

            scW[nl][l] = sv;
            const float p = 1.0f / (1.0f + __expf(-sv));
            const int slot = nl * stride;
            const float ppar = pp[slot][l];
            pp[slot][l]        = ppar * p;
            pp[slot + half][l] = ppar * (1.0f - p);
        }
        __syncthreads();
    }

    // ---------------- depth 7: fold leaf mixture, accumulate in VGPRs ----------------
    {
        float (*scP)[TS]  = (float(*)[TS])&scbuf[wbase[0]][0];   // d=6 scores (buf 6%3=0)
        float (*scP2)[TS] = (float(*)[TS])&scbuf[wbase[2]][0];   // d=5 scores (buf 5%3=2)

        for (int nl = wv; nl < 128; nl += 4) {
            const int n = 127 + nl;

            bf16x8 wh[4], wl_[4];
            #pragma unroll
            for (int t = 0; t < 4; ++t) {
                wh[t]  = Wh[(n * 4 + t) * 64 + l];
                wl_[t] = Wl[(n * 4 + t) * 64 + l];
            }
            const float4 b1q = ((const float4*)(b1 + n * 16))[quad];
            const float4 w2q = ((const float4*)(w2 + n * 16))[quad];
            const float4 wpq = ((const float4*)(W1 + (size_t)n * EFF + 128 * 16))[quad];
            const float4 wgq = ((const float4*)(W1 + (size_t)n * EFF + 129 * 16))[quad];
            const float  b2v = b2[n];
            const float* llp = leaf_logits + (size_t)(2 * nl) * NC;
            float lL[NC], lR[NC];
            #pragma unroll
            for (int c = 0; c < NC; ++c) { lL[c] = llp[c]; lR[c] = llp[NC + c]; }

            f32x4 acc[4] = {{0.f,0.f,0.f,0.f},{0.f,0.f,0.f,0.f},{0.f,0.f,0.f,0.f},{0.f,0.f,0.f,0.f}};
            #pragma unroll
            for (int t = 0; t < 4; ++t) {
                #pragma unroll
                for (int mt = 0; mt < 4; ++mt)
                    acc[mt] = __builtin_amdgcn_mfma_f32_16x16x32_bf16(wh[t],  xh[t][mt], acc[mt], 0, 0, 0);
                #pragma unroll
                for (int mt = 0; mt < 4; ++mt)
                    acc[mt] = __builtin_amdgcn_mfma_f32_16x16x32_bf16(wl_[t], xh[t][mt], acc[mt], 0, 0, 0);
                #pragma unroll
                for (int mt = 0; mt < 4; ++mt)
                    acc[mt] = __builtin_amdgcn_mfma_f32_16x16x32_bf16(wh[t],  xl[t][mt], acc[mt], 0, 0, 0);
            }

            float score01[4];
            #pragma unroll
            for (int mt = 0; mt < 4; ++mt) {
                const int scol = mt * 16 + col;
                const float par = scP[nl >> 1][scol];
                const float gp  = scP2[nl >> 2][scol];
                const f32x4 a = acc[mt];
                float ts = 0.0f;
                #pragma unroll
                for (int r = 0; r < 4; ++r) {
                    const float brr = (r == 0) ? b1q.x : (r == 1) ? b1q.y : (r == 2) ? b1q.z : b1q.w;
                    const float wpr = (r == 0) ? wpq.x : (r == 1) ? wpq.y : (r == 2) ? wpq.z : wpq.w;
                    const float wgr = (r == 0) ? wgq.x : (r == 1) ? wgq.y : (r == 2) ? wgq.z : wgq.w;
                    const float w2r = (r == 0) ? w2q.x : (r == 1) ? w2q.y : (r == 2) ? w2q.z : w2q.w;
                    const float h = a[r] + brr + par * wpr + gp * wgr;
                    ts = fmaf(fmaxf(h, 0.0f), w2r, ts);
                }
                ts += __shfl_xor(ts, 16);
                ts += __shfl_xor(ts, 32);
                score01[mt] = ts;
            }
            const float sa = (quad & 1) ? score01[1] : score01[0];
            const float sb = (quad & 1) ? score01[3] : score01[2];
            const float sv = ((quad & 2) ? sb : sa) + b2v;

            const float p = 1.0f / (1.0f + __expf(-sv));
            const float ppar = pp[nl][l];
            const float pL = ppar * p;
            const float pR = ppar * (1.0f - p);
            #pragma unroll
            for (int c = 0; c < NC; ++c)
                oacc[c] = fmaf(pL, lL[c], fmaf(pR, lR[c], oacc[c]));
        }
    }

    // ---------------- cross-wave out reduction through scbuf ----------------
    __syncthreads();                       // all waves done reading pp/scbuf
    {
        float* red = &scbuf[0][0];         // 4*64*10 = 2560 floats <= 7168
        #pragma unroll
        for (int c = 0; c < NC; ++c)
            red[(wv * 64 + l) * NC + c] = oacc[c];
    }
    __syncthreads();
    {
        const float* red = &scbuf[0][0];
        for (int i = tid; i < TS * NC; i += BLOCK) {
            float v = red[i] + red[640 + i] + red[1280 + i] + red[1920 + i];
            out[(size_t)s0 * NC + i] = v;
        }
    }
}

} // namespace

extern "C" void kernel_launch(void* const* d_in, const int* in_sizes, int n_in,
                              void* d_out, int out_size, void* d_ws, size_t ws_size,
                              hipStream_t stream) {
    const float* x           = (const float*)d_in[0];
    const float* path_prob   = (const float*)d_in[1];
    const float* W1          = (const float*)d_in[2];
    const float* b1          = (const float*)d_in[3];
    const float* w2          = (const float*)d_in[4];
    const float* b2          = (const float*)d_in[5];
    const float* leaf_logits = (const float*)d_in[6];
    float* out = (float*)d_out;

    const int batch = in_sizes[0] / IN_DIM;                // 32768
    const size_t fragElems = (size_t)NODES * 4 * 64 * 8;   // per precision
    unsigned short* bhi = (unsigned short*)d_ws;
    unsigned short* blo = bhi + fragElems;

    hipLaunchKernelGGL(prep_w1, dim3(NODES), dim3(256), 0, stream, W1, bhi, blo);
    hipLaunchKernelGGL(tree_mfma, dim3(batch / TS), dim3(BLOCK), 0, stream,
                       x, path_prob, W1, b1, w2, b2, leaf_logits, bhi, blo, out);
}

// Round 5
// 202.400 us; speedup vs baseline: 10.0552x; 1.0103x over previous
//
#include <hip/hip_runtime.h>
#include <math.h>

namespace {

typedef __attribute__((ext_vector_type(8))) short bf16x8;
typedef __attribute__((ext_vector_type(4))) float f32x4;

constexpr int IN_DIM = 128;
constexpr int EFF    = 130 * 16;   // W1 node stride (floats)
constexpr int NODES  = 255;
constexpr int TS     = 64;         // samples per block (4 MFMA N-tiles per wave)
constexpr int BLOCK  = 256;
constexpr int NC     = 10;

__device__ inline unsigned short f2bf(float f) {
    unsigned u = __float_as_uint(f);
    u += 0x7fff + ((u >> 16) & 1);          // RNE
    return (unsigned short)(u >> 16);
}
__device__ inline float bf2f(unsigned short h) {
    return __uint_as_float(((unsigned)h) << 16);
}

// ---- prep: W1[:, :128, :] -> MFMA fragment layout, bf16 hi/lo ----
// One block per node; coalesced float4 global reads via LDS staging.
// frag element (n, t, lane l, j): W[k = t*32 + (l>>4)*8 + j][hid = l&15]
__global__ __launch_bounds__(256) void prep_w1(const float* __restrict__ W1,
                                               unsigned short* __restrict__ bhi,
                                               unsigned short* __restrict__ blo) {
    __shared__ float xs[IN_DIM * 16];      // 8 KB: rows 0..127 of this node
    const int n = blockIdx.x, tid = threadIdx.x;
    const float4* src = (const float4*)(W1 + (size_t)n * EFF);
    ((float4*)xs)[tid]       = src[tid];
    ((float4*)xs)[tid + 256] = src[tid + 256];
    __syncthreads();
    const int l = tid & 63, t = tid >> 6;
    const int k0 = t * 32 + (l >> 4) * 8, hid = l & 15;
    bf16x8 hv, lv;
    #pragma unroll
    for (int j = 0; j < 8; ++j) {
        float v = xs[(k0 + j) * 16 + hid];
        unsigned short h = f2bf(v);
        hv[j] = (short)h;
        lv[j] = (short)f2bf(v - bf2f(h));
    }
    ((bf16x8*)bhi)[(n * 4 + t) * 64 + l] = hv;
    ((bf16x8*)blo)[(n * 4 + t) * 64 + l] = lv;
}

// ---- main fused tree kernel (transposed MFMA D[hid][s], TS=64, leaf-fold) ----
// waves_per_eu(2,2): LDS caps us at 2 blocks/CU (= 2 waves/EU) anyway, so let
// the allocator use the full 256-VGPR budget -> no scratch spills (R4 spilled
// ~54 MB at VGPR=128).
__global__ __launch_bounds__(BLOCK) __attribute__((amdgpu_waves_per_eu(2, 2)))
void tree_mfma(
    const float* __restrict__ x, const float* __restrict__ path_prob,
    const float* __restrict__ W1, const float* __restrict__ b1,
    const float* __restrict__ w2, const float* __restrict__ b2,
    const float* __restrict__ leaf_logits,
    const unsigned short* __restrict__ bhi, const unsigned short* __restrict__ blo,
    float* __restrict__ out)
{
    __shared__ float pp[128][TS];          // 32 KB: path probs, depths 0..6 only
    // exact-sized rotating score buffers: written at depth d -> buf d%3
    // buf0 (d=0,3,6): 64 rows @0; buf1 (d=1,4): 16 rows @64; buf2 (d=2,5): 32 rows @80
    __shared__ float scbuf[112][TS];       // 28 KB (reused for out-reduction)

    const int tid  = threadIdx.x;
    const int wv   = tid >> 6, l = tid & 63;
    const int quad = l >> 4,   col = l & 15;
    const int s0   = blockIdx.x * TS;

    if (tid < TS) pp[0][tid] = path_prob[s0 + tid];

    // x fragments (hi/lo) -> B operand: B[k = t*32+quad*8+j][col = sample&15]
    bf16x8 xh[4][4], xl[4][4];
    #pragma unroll
    for (int t = 0; t < 4; ++t)
        #pragma unroll
        for (int mt = 0; mt < 4; ++mt) {
            const float* xp = x + (size_t)(s0 + mt * 16 + col) * IN_DIM + t * 32 + quad * 8;
            float4 v0 = ((const float4*)xp)[0];
            float4 v1 = ((const float4*)xp)[1];
            float vv[8] = {v0.x, v0.y, v0.z, v0.w, v1.x, v1.y, v1.z, v1.w};
            bf16x8 hv, lv;
            #pragma unroll
            for (int j = 0; j < 8; ++j) {
                unsigned short h = f2bf(vv[j]);
                hv[j] = (short)h;
                lv[j] = (short)f2bf(vv[j] - bf2f(h));
            }
            xh[t][mt] = hv; xl[t][mt] = lv;
        }
    __syncthreads();

    const bf16x8* Wh = (const bf16x8*)bhi;
    const bf16x8* Wl = (const bf16x8*)blo;
    const int wbase[3] = {0, 64, 80};

    float oacc[NC];
    #pragma unroll
    for (int c = 0; c < NC; ++c) oacc[c] = 0.0f;

    // ---------------- depths 0..6 ----------------
    for (int d = 0; d < 7; ++d) {
        const int nd = 1 << d;
        float (*scW)[TS]  = (float(*)[TS])&scbuf[wbase[d % 3]][0];
        float (*scP)[TS]  = (float(*)[TS])&scbuf[wbase[(d + 2) % 3]][0];   // d-1
        float (*scP2)[TS] = (float(*)[TS])&scbuf[wbase[(d + 1) % 3]][0];   // d-2
        const int stride = 128 >> d, half = 64 >> d;

        for (int nl = wv; nl < nd; nl += 4) {
            const int n = nd - 1 + nl;

            bf16x8 wh[4], wl_[4];
            #pragma unroll
            for (int t = 0; t < 4; ++t) {
                wh[t]  = Wh[(n * 4 + t) * 64 + l];
                wl_[t] = Wl[(n * 4 + t) * 64 + l];
            }
            const float4 b1q = ((const float4*)(b1 + n * 16))[quad];
            const float4 w2q = ((const float4*)(w2 + n * 16))[quad];
            const float4 wpq = ((const float4*)(W1 + (size_t)n * EFF + 128 * 16))[quad];
            const float4 wgq = ((const float4*)(W1 + (size_t)n * EFF + 129 * 16))[quad];
            const float  b2v = b2[n];

            // bias folded into accumulator init (D row = hid = quad*4+r)
            f32x4 binit = {b1q.x, b1q.y, b1q.z, b1q.w};
            f32x4 acc[4] = {binit, binit, binit, binit};
            #pragma unroll
            for (int t = 0; t < 4; ++t) {
                #pragma unroll
                for (int mt = 0; mt < 4; ++mt)
                    acc[mt] = __builtin_amdgcn_mfma_f32_16x16x32_bf16(wh[t],  xh[t][mt], acc[mt], 0, 0, 0);
                #pragma unroll
                for (int mt = 0; mt < 4; ++mt)
                    acc[mt] = __builtin_amdgcn_mfma_f32_16x16x32_bf16(wl_[t], xh[t][mt], acc[mt], 0, 0, 0);
                #pragma unroll
                for (int mt = 0; mt < 4; ++mt)
                    acc[mt] = __builtin_amdgcn_mfma_f32_16x16x32_bf16(wh[t],  xl[t][mt], acc[mt], 0, 0, 0);
            }

            // epilogue: D[hid=quad*4+r][s=mt*16+col]; hid-reduce = 3 in-lane adds + 2 shfls
            float score01[4];
            #pragma unroll
            for (int mt = 0; mt < 4; ++mt) {
                const int scol = mt * 16 + col;
                const float par = (d >= 1) ? scP[nl >> 1][scol] : 0.0f;
                const float gp  = (d >= 2) ? scP2[nl >> 2][scol] : 0.0f;
                const f32x4 a = acc[mt];
                float ts = 0.0f;
                #pragma unroll
                for (int r = 0; r < 4; ++r) {
                    const float wpr = (r == 0) ? wpq.x : (r == 1) ? wpq.y : (r == 2) ? wpq.z : wpq.w;
                    const float wgr = (r == 0) ? wgq.x : (r == 1) ? wgq.y : (r == 2) ? wgq.z : wgq.w;
                    const float w2r = (r == 0) ? w2q.x : (r == 1) ? w2q.y : (r == 2) ? w2q.z : w2q.w;
                    const float h = fmaf(par, wpr, fmaf(gp, wgr, a[r]));
                    ts = fmaf(fmaxf(h, 0.0f), w2r, ts);
                }
                ts += __shfl_xor(ts, 16);
                ts += __shfl_xor(ts, 32);
                score01[mt] = ts;
            }
            // lane l owns sample l: select its score
            const float sa = (quad & 1) ? score01[1] : score01[0];
            const float sb = (quad & 1) ? score01[3] : score01[2];
            const float sv = ((quad & 2) ? sb : sa) + b2v;

            scW[nl][l] = sv;
            const float p = 1.0f / (1.0f + __expf(-sv));
            const int slot = nl * stride;
            const float ppar = pp[slot][l];
            pp[slot][l]        = ppar * p;
            pp[slot + half][l] = ppar * (1.0f - p);
        }
        __syncthreads();
    }

    // ---------------- depth 7: fold leaf mixture, accumulate in VGPRs ----------------
    {
        float (*scP)[TS]  = (float(*)[TS])&scbuf[wbase[0]][0];   // d=6 scores (buf 6%3=0)
        float (*scP2)[TS] = (float(*)[TS])&scbuf[wbase[2]][0];   // d=5 scores (buf 5%3=2)

        for (int nl = wv; nl < 128; nl += 4) {
            const int n = 127 + nl;

            bf16x8 wh[4], wl_[4];
            #pragma unroll
            for (int t = 0; t < 4; ++t) {
                wh[t]  = Wh[(n * 4 + t) * 64 + l];
                wl_[t] = Wl[(n * 4 + t) * 64 + l];
            }
            const float4 b1q = ((const float4*)(b1 + n * 16))[quad];
            const float4 w2q = ((const float4*)(w2 + n * 16))[quad];
            const float4 wpq = ((const float4*)(W1 + (size_t)n * EFF + 128 * 16))[quad];
            const float4 wgq = ((const float4*)(W1 + (size_t)n * EFF + 129 * 16))[quad];
            const float  b2v = b2[n];

            f32x4 binit = {b1q.x, b1q.y, b1q.z, b1q.w};
            f32x4 acc[4] = {binit, binit, binit, binit};
            #pragma unroll
            for (int t = 0; t < 4; ++t) {
                #pragma unroll
                for (int mt = 0; mt < 4; ++mt)
                    acc[mt] = __builtin_amdgcn_mfma_f32_16x16x32_bf16(wh[t],  xh[t][mt], acc[mt], 0, 0, 0);
                #pragma unroll
                for (int mt = 0; mt < 4; ++mt)
                    acc[mt] = __builtin_amdgcn_mfma_f32_16x16x32_bf16(wl_[t], xh[t][mt], acc[mt], 0, 0, 0);
                #pragma unroll
                for (int mt = 0; mt < 4; ++mt)
                    acc[mt] = __builtin_amdgcn_mfma_f32_16x16x32_bf16(wh[t],  xl[t][mt], acc[mt], 0, 0, 0);
            }

            float score01[4];
            #pragma unroll
            for (int mt = 0; mt < 4; ++mt) {
                const int scol = mt * 16 + col;
                const float par = scP[nl >> 1][scol];
                const float gp  = scP2[nl >> 2][scol];
                const f32x4 a = acc[mt];
                float ts = 0.0f;
                #pragma unroll
                for (int r = 0; r < 4; ++r) {
                    const float wpr = (r == 0) ? wpq.x : (r == 1) ? wpq.y : (r == 2) ? wpq.z : wpq.w;
                    const float wgr = (r == 0) ? wgq.x : (r == 1) ? wgq.y : (r == 2) ? wgq.z : wgq.w;
                    const float w2r = (r == 0) ? w2q.x : (r == 1) ? w2q.y : (r == 2) ? w2q.z : w2q.w;
                    const float h = fmaf(par, wpr, fmaf(gp, wgr, a[r]));
                    ts = fmaf(fmaxf(h, 0.0f), w2r, ts);
                }
                ts += __shfl_xor(ts, 16);
                ts += __shfl_xor(ts, 32);
                score01[mt] = ts;
            }
            const float sa = (quad & 1) ? score01[1] : score01[0];
            const float sb = (quad & 1) ? score01[3] : score01[2];
            const float sv = ((quad & 2) ? sb : sa) + b2v;

            const float p = 1.0f / (1.0f + __expf(-sv));
            const float ppar = pp[nl][l];
            const float pL = ppar * p;
            const float pR = ppar * (1.0f - p);
            // leaf logits loaded late: short live range keeps us under 256 VGPRs
            const float* llp = leaf_logits + (size_t)(2 * nl) * NC;
            #pragma unroll
            for (int c = 0; c < NC; ++c)
                oacc[c] = fmaf(pL, llp[c], fmaf(pR, llp[NC + c], oacc[c]));
        }
    }

    // ---------------- cross-wave out reduction through scbuf ----------------
    __syncthreads();                       // all waves done reading pp/scbuf
    {
        float* red = &scbuf[0][0];         // 4*64*10 = 2560 floats <= 7168
        #pragma unroll
        for (int c = 0; c < NC; ++c)
            red[(wv * 64 + l) * NC + c] = oacc[c];
    }
    __syncthreads();
    {
        const float* red = &scbuf[0][0];
        for (int i = tid; i < TS * NC; i += BLOCK) {
            float v = red[i] + red[640 + i] + red[1280 + i] + red[1920 + i];
            out[(size_t)s0 * NC + i] = v;
        }
    }
}

} // namespace

extern "C" void kernel_launch(void* const* d_in, const int* in_sizes, int n_in,
                              void* d_out, int out_size, void* d_ws, size_t ws_size,
                              hipStream_t stream) {
    const float* x           = (const float*)d_in[0];
    const float* path_prob   = (const float*)d_in[1];
    const float* W1          = (const float*)d_in[2];
    const float* b1          = (const float*)d_in[3];
    const float* w2          = (const float*)d_in[4];
    const float* b2          = (const float*)d_in[5];
    const float* leaf_logits = (const float*)d_in[6];
    float* out = (float*)d_out;

    const int batch = in_sizes[0] / IN_DIM;                // 32768
    const size_t fragElems = (size_t)NODES * 4 * 64 * 8;   // per precision
    unsigned short* bhi = (unsigned short*)d_ws;
    unsigned short* blo = bhi + fragElems;

    hipLaunchKernelGGL(prep_w1, dim3(NODES), dim3(256), 0, stream, W1, bhi, blo);
    hipLaunchKernelGGL(tree_mfma, dim3(batch / TS), dim3(BLOCK), 0, stream,
                       x, path_prob, W1, b1, w2, b2, leaf_logits, bhi, blo, out);
}

// Round 6
// 188.741 us; speedup vs baseline: 10.7829x; 1.0724x over previous
//
#include <hip/hip_runtime.h>
#include <math.h>

namespace {

typedef __attribute__((ext_vector_type(8))) short bf16x8;
typedef __attribute__((ext_vector_type(4))) float f32x4;

constexpr int IN_DIM = 128;
constexpr int EFF    = 130 * 16;   // W1 node stride (floats)
constexpr int NODES  = 255;
constexpr int TS     = 64;         // samples per block (4 MFMA N-tiles per wave)
constexpr int BLOCK  = 256;
constexpr int NC     = 10;

__device__ inline unsigned short f2bf(float f) {
    unsigned u = __float_as_uint(f);
    u += 0x7fff + ((u >> 16) & 1);          // RNE
    return (unsigned short)(u >> 16);
}
__device__ inline float bf2f(unsigned short h) {
    return __uint_as_float(((unsigned)h) << 16);
}

// ---- prep: W1[:, :128, :] -> MFMA fragment layout, bf16 hi/lo ----
// One block per node; coalesced float4 global reads via LDS staging.
// frag element (n, t, lane l, j): W[k = t*32 + (l>>4)*8 + j][hid = l&15]
__global__ __launch_bounds__(256) void prep_w1(const float* __restrict__ W1,
                                               unsigned short* __restrict__ bhi,
                                               unsigned short* __restrict__ blo) {
    __shared__ float xs[IN_DIM * 16];      // 8 KB: rows 0..127 of this node
    const int n = blockIdx.x, tid = threadIdx.x;
    const float4* src = (const float4*)(W1 + (size_t)n * EFF);
    ((float4*)xs)[tid]       = src[tid];
    ((float4*)xs)[tid + 256] = src[tid + 256];
    __syncthreads();
    const int l = tid & 63, t = tid >> 6;
    const int k0 = t * 32 + (l >> 4) * 8, hid = l & 15;
    bf16x8 hv, lv;
    #pragma unroll
    for (int j = 0; j < 8; ++j) {
        float v = xs[(k0 + j) * 16 + hid];
        unsigned short h = f2bf(v);
        hv[j] = (short)h;
        lv[j] = (short)f2bf(v - bf2f(h));
    }
    ((bf16x8*)bhi)[(n * 4 + t) * 64 + l] = hv;
    ((bf16x8*)blo)[(n * 4 + t) * 64 + l] = lv;
}

// ---- main fused tree kernel ----
// VGPR-class budget discipline (gfx950 splits the unified file; arch-VGPR cap
// observed at 128): xh stays in regs (64), xl lives in LDS (wave-invariant,
// read per t-iter), W-frags streamed per t (live 8-16), acc -> AGPRs.
__global__ __launch_bounds__(BLOCK) __attribute__((amdgpu_waves_per_eu(2, 2)))
void tree_mfma(
    const float* __restrict__ x, const float* __restrict__ path_prob,
    const float* __restrict__ W1, const float* __restrict__ b1,
    const float* __restrict__ w2, const float* __restrict__ b2,
    const float* __restrict__ leaf_logits,
    const unsigned short* __restrict__ bhi, const unsigned short* __restrict__ blo,
    float* __restrict__ out)
{
    __shared__ float pp[128][TS];          // 32 KB: path probs, depths 0..6 only
    // exact-sized rotating score buffers: written at depth d -> buf d%3
    // buf0 (d=0,3,6): 64 rows @0; buf1 (d=1,4): 16 rows @64; buf2 (d=2,5): 32 rows @80
    __shared__ float scbuf[112][TS];       // 28 KB (reused for out-reduction)
    __shared__ bf16x8 xlbuf[4][4][64];     // 16 KB: x low-order fragments [t][mt][lane]

    const int tid  = threadIdx.x;
    const int wv   = tid >> 6, l = tid & 63;
    const int quad = l >> 4,   col = l & 15;
    const int s0   = blockIdx.x * TS;

    if (tid < TS) pp[0][tid] = path_prob[s0 + tid];

    // x fragments: B operand B[k = t*32+quad*8+j][col]. hi in VGPRs; lo -> LDS.
    bf16x8 xh[4][4];
    #pragma unroll
    for (int t = 0; t < 4; ++t)
        #pragma unroll
        for (int mt = 0; mt < 4; ++mt) {
            const float* xp = x + (size_t)(s0 + mt * 16 + col) * IN_DIM + t * 32 + quad * 8;
            float4 v0 = ((const float4*)xp)[0];
            float4 v1 = ((const float4*)xp)[1];
            float vv[8] = {v0.x, v0.y, v0.z, v0.w, v1.x, v1.y, v1.z, v1.w};
            bf16x8 hv, lv;
            #pragma unroll
            for (int j = 0; j < 8; ++j) {
                unsigned short h = f2bf(vv[j]);
                hv[j] = (short)h;
                lv[j] = (short)f2bf(vv[j] - bf2f(h));
            }
            xh[t][mt] = hv;
            if (mt == wv) xlbuf[t][mt][l] = lv;   // each wave owns mt == wv
        }
    __syncthreads();

    const bf16x8* Wh = (const bf16x8*)bhi;
    const bf16x8* Wl = (const bf16x8*)blo;
    const int wbase[3] = {0, 64, 80};

    // ---------------- depths 0..6 ----------------
    for (int d = 0; d < 7; ++d) {
        const int nd = 1 << d;
        float (*scW)[TS]  = (float(*)[TS])&scbuf[wbase[d % 3]][0];
        float (*scP)[TS]  = (float(*)[TS])&scbuf[wbase[(d + 2) % 3]][0];   // d-1
        float (*scP2)[TS] = (float(*)[TS])&scbuf[wbase[(d + 1) % 3]][0];   // d-2
        const int stride = 128 >> d, half = 64 >> d;

        for (int nl = wv; nl < nd; nl += 4) {
            const int n = nd - 1 + nl;

            const float4 b1q = ((const float4*)(b1 + n * 16))[quad];
            f32x4 binit = {b1q.x, b1q.y, b1q.z, b1q.w};
            f32x4 acc[4] = {binit, binit, binit, binit};

            #pragma unroll
            for (int t = 0; t < 4; ++t) {
                const bf16x8 wh  = Wh[(n * 4 + t) * 64 + l];
                const bf16x8 wl_ = Wl[(n * 4 + t) * 64 + l];
                const bf16x8 xl0 = xlbuf[t][0][l];
                const bf16x8 xl1 = xlbuf[t][1][l];
                const bf16x8 xl2 = xlbuf[t][2][l];
                const bf16x8 xl3 = xlbuf[t][3][l];
                #pragma unroll
                for (int mt = 0; mt < 4; ++mt)
                    acc[mt] = __builtin_amdgcn_mfma_f32_16x16x32_bf16(wh,  xh[t][mt], acc[mt], 0, 0, 0);
                #pragma unroll
                for (int mt = 0; mt < 4; ++mt)
                    acc[mt] = __builtin_amdgcn_mfma_f32_16x16x32_bf16(wl_, xh[t][mt], acc[mt], 0, 0, 0);
                acc[0] = __builtin_amdgcn_mfma_f32_16x16x32_bf16(wh, xl0, acc[0], 0, 0, 0);
                acc[1] = __builtin_amdgcn_mfma_f32_16x16x32_bf16(wh, xl1, acc[1], 0, 0, 0);
                acc[2] = __builtin_amdgcn_mfma_f32_16x16x32_bf16(wh, xl2, acc[2], 0, 0, 0);
                acc[3] = __builtin_amdgcn_mfma_f32_16x16x32_bf16(wh, xl3, acc[3], 0, 0, 0);
            }

            // epilogue scalars loaded late (short live ranges)
            const float4 w2q = ((const float4*)(w2 + n * 16))[quad];
            const float4 wpq = ((const float4*)(W1 + (size_t)n * EFF + 128 * 16))[quad];
            const float4 wgq = ((const float4*)(W1 + (size_t)n * EFF + 129 * 16))[quad];
            const float  b2v = b2[n];

            // epilogue: D[hid=quad*4+r][s=mt*16+col]; hid-reduce = 3 in-lane adds + 2 shfls
            float score01[4];
            #pragma unroll
            for (int mt = 0; mt < 4; ++mt) {
                const int scol = mt * 16 + col;
                const float par = (d >= 1) ? scP[nl >> 1][scol] : 0.0f;
                const float gp  = (d >= 2) ? scP2[nl >> 2][scol] : 0.0f;
                const f32x4 a = acc[mt];
                float ts = 0.0f;
                #pragma unroll
                for (int r = 0; r < 4; ++r) {
                    const float wpr = (r == 0) ? wpq.x : (r == 1) ? wpq.y : (r == 2) ? wpq.z : wpq.w;
                    const float wgr = (r == 0) ? wgq.x : (r == 1) ? wgq.y : (r == 2) ? wgq.z : wgq.w;
                    const float w2r = (r == 0) ? w2q.x : (r == 1) ? w2q.y : (r == 2) ? w2q.z : w2q.w;
                    const float h = fmaf(par, wpr, fmaf(gp, wgr, a[r]));
                    ts = fmaf(fmaxf(h, 0.0f), w2r, ts);
                }
                ts += __shfl_xor(ts, 16);
                ts += __shfl_xor(ts, 32);
                score01[mt] = ts;
            }
            // lane l owns sample l: select its score
            const float sa = (quad & 1) ? score01[1] : score01[0];
            const float sb = (quad & 1) ? score01[3] : score01[2];
            const float sv = ((quad & 2) ? sb : sa) + b2v;

            scW[nl][l] = sv;
            const float p = 1.0f / (1.0f + __expf(-sv));
            const int slot = nl * stride;
            const float ppar = pp[slot][l];
            pp[slot][l]        = ppar * p;
            pp[slot + half][l] = ppar * (1.0f - p);
        }
        __syncthreads();
    }

    // ---------------- depth 7: fold leaf mixture, accumulate in VGPRs ----------------
    float oacc[NC];
    #pragma unroll
    for (int c = 0; c < NC; ++c) oacc[c] = 0.0f;
    {
        float (*scP)[TS]  = (float(*)[TS])&scbuf[wbase[0]][0];   // d=6 scores (buf 6%3=0)
        float (*scP2)[TS] = (float(*)[TS])&scbuf[wbase[2]][0];   // d=5 scores (buf 5%3=2)

        for (int nl = wv; nl < 128; nl += 4) {
            const int n = 127 + nl;

            const float4 b1q = ((const float4*)(b1 + n * 16))[quad];
            f32x4 binit = {b1q.x, b1q.y, b1q.z, b1q.w};
            f32x4 acc[4] = {binit, binit, binit, binit};

            #pragma unroll
            for (int t = 0; t < 4; ++t) {
                const bf16x8 wh  = Wh[(n * 4 + t) * 64 + l];
                const bf16x8 wl_ = Wl[(n * 4 + t) * 64 + l];
                const bf16x8 xl0 = xlbuf[t][0][l];
                const bf16x8 xl1 = xlbuf[t][1][l];
                const bf16x8 xl2 = xlbuf[t][2][l];
                const bf16x8 xl3 = xlbuf[t][3][l];
                #pragma unroll
                for (int mt = 0; mt < 4; ++mt)
                    acc[mt] = __builtin_amdgcn_mfma_f32_16x16x32_bf16(wh,  xh[t][mt], acc[mt], 0, 0, 0);
                #pragma unroll
                for (int mt = 0; mt < 4; ++mt)
                    acc[mt] = __builtin_amdgcn_mfma_f32_16x16x32_bf16(wl_, xh[t][mt], acc[mt], 0, 0, 0);
                acc[0] = __builtin_amdgcn_mfma_f32_16x16x32_bf16(wh, xl0, acc[0], 0, 0, 0);
                acc[1] = __builtin_amdgcn_mfma_f32_16x16x32_bf16(wh, xl1, acc[1], 0, 0, 0);
                acc[2] = __builtin_amdgcn_mfma_f32_16x16x32_bf16(wh, xl2, acc[2], 0, 0, 0);
                acc[3] = __builtin_amdgcn_mfma_f32_16x16x32_bf16(wh, xl3, acc[3], 0, 0, 0);
            }

            const float4 w2q = ((const float4*)(w2 + n * 16))[quad];
            const float4 wpq = ((const float4*)(W1 + (size_t)n * EFF + 128 * 16))[quad];
            const float4 wgq = ((const float4*)(W1 + (size_t)n * EFF + 129 * 16))[quad];
            const float  b2v = b2[n];

            float score01[4];
            #pragma unroll
            for (int mt = 0; mt < 4; ++mt) {
                const int scol = mt * 16 + col;
                const float par = scP[nl >> 1][scol];
                const float gp  = scP2[nl >> 2][scol];
                const f32x4 a = acc[mt];
                float ts = 0.0f;
                #pragma unroll
                for (int r = 0; r < 4; ++r) {
                    const float wpr = (r == 0) ? wpq.x : (r == 1) ? wpq.y : (r == 2) ? wpq.z : wpq.w;
                    const float wgr = (r == 0) ? wgq.x : (r == 1) ? wgq.y : (r == 2) ? wgq.z : wgq.w;
                    const float w2r = (r == 0) ? w2q.x : (r == 1) ? w2q.y : (r == 2) ? w2q.z : w2q.w;
                    const float h = fmaf(par, wpr, fmaf(gp, wgr, a[r]));
                    ts = fmaf(fmaxf(h, 0.0f), w2r, ts);
                }
                ts += __shfl_xor(ts, 16);
                ts += __shfl_xor(ts, 32);
                score01[mt] = ts;
            }
            const float sa = (quad & 1) ? score01[1] : score01[0];
            const float sb = (quad & 1) ? score01[3] : score01[2];
            const float sv = ((quad & 2) ? sb : sa) + b2v;

            const float p = 1.0f / (1.0f + __expf(-sv));
            const float ppar = pp[nl][l];
            const float pL = ppar * p;
            const float pR = ppar * (1.0f - p);
            // leaf logits loaded late: short live range
            const float* llp = leaf_logits + (size_t)(2 * nl) * NC;
            #pragma unroll
            for (int c = 0; c < NC; ++c)
                oacc[c] = fmaf(pL, llp[c], fmaf(pR, llp[NC + c], oacc[c]));
        }
    }

    // ---------------- cross-wave out reduction through scbuf ----------------
    __syncthreads();                       // all waves done reading pp/scbuf
    {
        float* red = &scbuf[0][0];         // 4*64*10 = 2560 floats <= 7168
        #pragma unroll
        for (int c = 0; c < NC; ++c)
            red[(wv * 64 + l) * NC + c] = oacc[c];
    }
    __syncthreads();
    {
        const float* red = &scbuf[0][0];
        for (int i = tid; i < TS * NC; i += BLOCK) {
            float v = red[i] + red[640 + i] + red[1280 + i] + red[1920 + i];
            out[(size_t)s0 * NC + i] = v;
        }
    }
}

} // namespace

extern "C" void kernel_launch(void* const* d_in, const int* in_sizes, int n_in,
                              void* d_out, int out_size, void* d_ws, size_t ws_size,
                              hipStream_t stream) {
    const float* x           = (const float*)d_in[0];
    const float* path_prob   = (const float*)d_in[1];
    const float* W1          = (const float*)d_in[2];
    const float* b1          = (const float*)d_in[3];
    const float* w2          = (const float*)d_in[4];
    const float* b2          = (const float*)d_in[5];
    const float* leaf_logits = (const float*)d_in[6];
    float* out = (float*)d_out;

    const int batch = in_sizes[0] / IN_DIM;                // 32768
    const size_t fragElems = (size_t)NODES * 4 * 64 * 8;   // per precision
    unsigned short* bhi = (unsigned short*)d_ws;
    unsigned short* blo = bhi + fragElems;

    hipLaunchKernelGGL(prep_w1, dim3(NODES), dim3(256), 0, stream, W1, bhi, blo);
    hipLaunchKernelGGL(tree_mfma, dim3(batch / TS), dim3(BLOCK), 0, stream,
                       x, path_prob, W1, b1, w2, b2, leaf_logits, bhi, blo, out);
}

// Round 7
// 182.595 us; speedup vs baseline: 11.1458x; 1.0337x over previous
//
#include <hip/hip_runtime.h>
#include <math.h>

namespace {

typedef __attribute__((ext_vector_type(8))) short bf16x8;
typedef __attribute__((ext_vector_type(4))) float f32x4;

constexpr int IN_DIM = 128;
constexpr int EFF    = 130 * 16;   // W1 node stride (floats)
constexpr int NODES  = 255;
constexpr int TS     = 64;         // samples per block (4 MFMA N-tiles per wave)
constexpr int BLOCK  = 256;
constexpr int NC     = 10;

__device__ inline unsigned short f2bf(float f) {
    unsigned u = __float_as_uint(f);
    u += 0x7fff + ((u >> 16) & 1);          // RNE
    return (unsigned short)(u >> 16);
}
__device__ inline float bf2f(unsigned short h) {
    return __uint_as_float(((unsigned)h) << 16);
}

// ---- prep: W1[:, :128, :] -> MFMA fragment layout, bf16 hi/lo ----
// One block per node; coalesced float4 global reads via LDS staging.
// frag element (n, t, lane l, j): W[k = t*32 + (l>>4)*8 + j][hid = l&15]
__global__ __launch_bounds__(256) void prep_w1(const float* __restrict__ W1,
                                               unsigned short* __restrict__ bhi,
                                               unsigned short* __restrict__ blo) {
    __shared__ float xs[IN_DIM * 16];      // 8 KB: rows 0..127 of this node
    const int n = blockIdx.x, tid = threadIdx.x;
    const float4* src = (const float4*)(W1 + (size_t)n * EFF);
    ((float4*)xs)[tid]       = src[tid];
    ((float4*)xs)[tid + 256] = src[tid + 256];
    __syncthreads();
    const int l = tid & 63, t = tid >> 6;
    const int k0 = t * 32 + (l >> 4) * 8, hid = l & 15;
    bf16x8 hv, lv;
    #pragma unroll
    for (int j = 0; j < 8; ++j) {
        float v = xs[(k0 + j) * 16 + hid];
        unsigned short h = f2bf(v);
        hv[j] = (short)h;
        lv[j] = (short)f2bf(v - bf2f(h));
    }
    ((bf16x8*)bhi)[(n * 4 + t) * 64 + l] = hv;
    ((bf16x8*)blo)[(n * 4 + t) * 64 + l] = lv;
}

// ---- main fused tree kernel ----
// R7: latency-oriented scheduling. All epilogue operands hoisted to iter
// start (hidden under ~930 cyc of MFMA); Wh/Wl software-prefetched one
// t-step ahead. Arithmetic identical to R6 (absmax must not move).
__global__ __launch_bounds__(BLOCK) __attribute__((amdgpu_waves_per_eu(2, 2)))
void tree_mfma(
    const float* __restrict__ x, const float* __restrict__ path_prob,
    const float* __restrict__ W1, const float* __restrict__ b1,
    const float* __restrict__ w2, const float* __restrict__ b2,
    const float* __restrict__ leaf_logits,
    const unsigned short* __restrict__ bhi, const unsigned short* __restrict__ blo,
    float* __restrict__ out)
{
    __shared__ float pp[128][TS];          // 32 KB: path probs, depths 0..6 only
    // exact-sized rotating score buffers: written at depth d -> buf d%3
    // buf0 (d=0,3,6): 64 rows @0; buf1 (d=1,4): 16 rows @64; buf2 (d=2,5): 32 rows @80
    __shared__ float scbuf[112][TS];       // 28 KB (reused for out-reduction)
    __shared__ bf16x8 xlbuf[4][4][64];     // 16 KB: x low-order fragments [t][mt][lane]

    const int tid  = threadIdx.x;
    const int wv   = tid >> 6, l = tid & 63;
    const int quad = l >> 4,   col = l & 15;
    const int s0   = blockIdx.x * TS;

    if (tid < TS) pp[0][tid] = path_prob[s0 + tid];

    // x fragments: B operand B[k = t*32+quad*8+j][col]. hi in VGPRs; lo -> LDS.
    bf16x8 xh[4][4];
    #pragma unroll
    for (int t = 0; t < 4; ++t)
        #pragma unroll
        for (int mt = 0; mt < 4; ++mt) {
            const float* xp = x + (size_t)(s0 + mt * 16 + col) * IN_DIM + t * 32 + quad * 8;
            float4 v0 = ((const float4*)xp)[0];
            float4 v1 = ((const float4*)xp)[1];
            float vv[8] = {v0.x, v0.y, v0.z, v0.w, v1.x, v1.y, v1.z, v1.w};
            bf16x8 hv, lv;
            #pragma unroll
            for (int j = 0; j < 8; ++j) {
                unsigned short h = f2bf(vv[j]);
                hv[j] = (short)h;
                lv[j] = (short)f2bf(vv[j] - bf2f(h));
            }
            xh[t][mt] = hv;
            if (mt == wv) xlbuf[t][mt][l] = lv;   // each wave owns mt == wv
        }
    __syncthreads();

    const bf16x8* Wh = (const bf16x8*)bhi;
    const bf16x8* Wl = (const bf16x8*)blo;
    const int wbase[3] = {0, 64, 80};

    // ---------------- depths 0..6 ----------------
    for (int d = 0; d < 7; ++d) {
        const int nd = 1 << d;
        float (*scW)[TS]  = (float(*)[TS])&scbuf[wbase[d % 3]][0];
        float (*scP)[TS]  = (float(*)[TS])&scbuf[wbase[(d + 2) % 3]][0];   // d-1
        float (*scP2)[TS] = (float(*)[TS])&scbuf[wbase[(d + 1) % 3]][0];   // d-2
        const int stride = 128 >> d, half = 64 >> d;

        for (int nl = wv; nl < nd; nl += 4) {
            const int n = nd - 1 + nl;

            // ---- hoisted operands: latency hidden under the MFMA block ----
            const float4 b1q = ((const float4*)(b1 + n * 16))[quad];
            const float4 w2q = ((const float4*)(w2 + n * 16))[quad];
            const float4 wpq = ((const float4*)(W1 + (size_t)n * EFF + 128 * 16))[quad];
            const float4 wgq = ((const float4*)(W1 + (size_t)n * EFF + 129 * 16))[quad];
            const float  b2v = b2[n];
            const int    slot = nl * stride;
            const float  ppar = pp[slot][l];
            float par[4], gp[4];
            #pragma unroll
            for (int mt = 0; mt < 4; ++mt) {
                const int scol = mt * 16 + col;
                par[mt] = (d >= 1) ? scP[nl >> 1][scol] : 0.0f;
                gp[mt]  = (d >= 2) ? scP2[nl >> 2][scol] : 0.0f;
            }

            // ---- MFMA t-loop with W prefetch (rotating regs) ----
            const bf16x8* whp = Wh + (size_t)n * 256 + l;
            const bf16x8* wlp = Wl + (size_t)n * 256 + l;
            bf16x8 whc = whp[0], wlc = wlp[0];

            f32x4 binit = {b1q.x, b1q.y, b1q.z, b1q.w};
            f32x4 acc[4] = {binit, binit, binit, binit};
            #pragma unroll
            for (int t = 0; t < 4; ++t) {
                bf16x8 whn, wln;
                if (t < 3) { whn = whp[(t + 1) * 64]; wln = wlp[(t + 1) * 64]; }
                const bf16x8 xl0 = xlbuf[t][0][l];
                const bf16x8 xl1 = xlbuf[t][1][l];
                const bf16x8 xl2 = xlbuf[t][2][l];
                const bf16x8 xl3 = xlbuf[t][3][l];
                #pragma unroll
                for (int mt = 0; mt < 4; ++mt)
                    acc[mt] = __builtin_amdgcn_mfma_f32_16x16x32_bf16(whc, xh[t][mt], acc[mt], 0, 0, 0);
                #pragma unroll
                for (int mt = 0; mt < 4; ++mt)
                    acc[mt] = __builtin_amdgcn_mfma_f32_16x16x32_bf16(wlc, xh[t][mt], acc[mt], 0, 0, 0);
                acc[0] = __builtin_amdgcn_mfma_f32_16x16x32_bf16(whc, xl0, acc[0], 0, 0, 0);
                acc[1] = __builtin_amdgcn_mfma_f32_16x16x32_bf16(whc, xl1, acc[1], 0, 0, 0);
                acc[2] = __builtin_amdgcn_mfma_f32_16x16x32_bf16(whc, xl2, acc[2], 0, 0, 0);
                acc[3] = __builtin_amdgcn_mfma_f32_16x16x32_bf16(whc, xl3, acc[3], 0, 0, 0);
                if (t < 3) { whc = whn; wlc = wln; }
            }

            // epilogue: D[hid=quad*4+r][s=mt*16+col]; hid-reduce = 3 in-lane adds + 2 shfls
            float score01[4];
            #pragma unroll
            for (int mt = 0; mt < 4; ++mt) {
                const f32x4 a = acc[mt];
                const float pa = par[mt], ga = gp[mt];
                float ts = 0.0f;
                #pragma unroll
                for (int r = 0; r < 4; ++r) {
                    const float wpr = (r == 0) ? wpq.x : (r == 1) ? wpq.y : (r == 2) ? wpq.z : wpq.w;
                    const float wgr = (r == 0) ? wgq.x : (r == 1) ? wgq.y : (r == 2) ? wgq.z : wgq.w;
                    const float w2r = (r == 0) ? w2q.x : (r == 1) ? w2q.y : (r == 2) ? w2q.z : w2q.w;
                    const float h = fmaf(pa, wpr, fmaf(ga, wgr, a[r]));
                    ts = fmaf(fmaxf(h, 0.0f), w2r, ts);
                }
                ts += __shfl_xor(ts, 16);
                ts += __shfl_xor(ts, 32);
                score01[mt] = ts;
            }
            // lane l owns sample l: select its score
            const float sa = (quad & 1) ? score01[1] : score01[0];
            const float sb = (quad & 1) ? score01[3] : score01[2];
            const float sv = ((quad & 2) ? sb : sa) + b2v;

            scW[nl][l] = sv;
            const float p = 1.0f / (1.0f + __expf(-sv));
            pp[slot][l]        = ppar * p;
            pp[slot + half][l] = ppar * (1.0f - p);
        }
        __syncthreads();
    }

    // ---------------- depth 7: fold leaf mixture, accumulate in VGPRs ----------------
    float oacc[NC];
    #pragma unroll
    for (int c = 0; c < NC; ++c) oacc[c] = 0.0f;
    {
        float (*scP)[TS]  = (float(*)[TS])&scbuf[wbase[0]][0];   // d=6 scores (buf 6%3=0)
        float (*scP2)[TS] = (float(*)[TS])&scbuf[wbase[2]][0];   // d=5 scores (buf 5%3=2)

        for (int nl = wv; nl < 128; nl += 4) {
            const int n = 127 + nl;

            const float4 b1q = ((const float4*)(b1 + n * 16))[quad];
            const float4 w2q = ((const float4*)(w2 + n * 16))[quad];
            const float4 wpq = ((const float4*)(W1 + (size_t)n * EFF + 128 * 16))[quad];
            const float4 wgq = ((const float4*)(W1 + (size_t)n * EFF + 129 * 16))[quad];
            const float  b2v = b2[n];
            const float  ppar = pp[nl][l];
            float par[4], gp[4];
            #pragma unroll
            for (int mt = 0; mt < 4; ++mt) {
                const int scol = mt * 16 + col;
                par[mt] = scP[nl >> 1][scol];
                gp[mt]  = scP2[nl >> 2][scol];
            }

            const bf16x8* whp = Wh + (size_t)n * 256 + l;
            const bf16x8* wlp = Wl + (size_t)n * 256 + l;
            bf16x8 whc = whp[0], wlc = wlp[0];

            f32x4 binit = {b1q.x, b1q.y, b1q.z, b1q.w};
            f32x4 acc[4] = {binit, binit, binit, binit};
            #pragma unroll
            for (int t = 0; t < 4; ++t) {
                bf16x8 whn, wln;
                if (t < 3) { whn = whp[(t + 1) * 64]; wln = wlp[(t + 1) * 64]; }
                const bf16x8 xl0 = xlbuf[t][0][l];
                const bf16x8 xl1 = xlbuf[t][1][l];
                const bf16x8 xl2 = xlbuf[t][2][l];
                const bf16x8 xl3 = xlbuf[t][3][l];
                #pragma unroll
                for (int mt = 0; mt < 4; ++mt)
                    acc[mt] = __builtin_amdgcn_mfma_f32_16x16x32_bf16(whc, xh[t][mt], acc[mt], 0, 0, 0);
                #pragma unroll
                for (int mt = 0; mt < 4; ++mt)
                    acc[mt] = __builtin_amdgcn_mfma_f32_16x16x32_bf16(wlc, xh[t][mt], acc[mt], 0, 0, 0);
                acc[0] = __builtin_amdgcn_mfma_f32_16x16x32_bf16(whc, xl0, acc[0], 0, 0, 0);
                acc[1] = __builtin_amdgcn_mfma_f32_16x16x32_bf16(whc, xl1, acc[1], 0, 0, 0);
                acc[2] = __builtin_amdgcn_mfma_f32_16x16x32_bf16(whc, xl2, acc[2], 0, 0, 0);
                acc[3] = __builtin_amdgcn_mfma_f32_16x16x32_bf16(whc, xl3, acc[3], 0, 0, 0);
                if (t < 3) { whc = whn; wlc = wln; }
            }

            float score01[4];
            #pragma unroll
            for (int mt = 0; mt < 4; ++mt) {
                const f32x4 a = acc[mt];
                const float pa = par[mt], ga = gp[mt];
                float ts = 0.0f;
                #pragma unroll
                for (int r = 0; r < 4; ++r) {
                    const float wpr = (r == 0) ? wpq.x : (r == 1) ? wpq.y : (r == 2) ? wpq.z : wpq.w;
                    const float wgr = (r == 0) ? wgq.x : (r == 1) ? wgq.y : (r == 2) ? wgq.z : wgq.w;
                    const float w2r = (r == 0) ? w2q.x : (r == 1) ? w2q.y : (r == 2) ? w2q.z : w2q.w;
                    const float h = fmaf(pa, wpr, fmaf(ga, wgr, a[r]));
                    ts = fmaf(fmaxf(h, 0.0f), w2r, ts);
                }
                ts += __shfl_xor(ts, 16);
                ts += __shfl_xor(ts, 32);
                score01[mt] = ts;
            }
            const float sa = (quad & 1) ? score01[1] : score01[0];
            const float sb = (quad & 1) ? score01[3] : score01[2];
            const float sv = ((quad & 2) ? sb : sa) + b2v;

            const float p = 1.0f / (1.0f + __expf(-sv));
            const float pL = ppar * p;
            const float pR = ppar * (1.0f - p);
            const float* llp = leaf_logits + (size_t)(2 * nl) * NC;
            #pragma unroll
            for (int c = 0; c < NC; ++c)
                oacc[c] = fmaf(pL, llp[c], fmaf(pR, llp[NC + c], oacc[c]));
        }
    }

    // ---------------- cross-wave out reduction through scbuf ----------------
    __syncthreads();                       // all waves done reading pp/scbuf
    {
        float* red = &scbuf[0][0];         // 4*64*10 = 2560 floats <= 7168
        #pragma unroll
        for (int c = 0; c < NC; ++c)
            red[(wv * 64 + l) * NC + c] = oacc[c];
    }
    __syncthreads();
    {
        const float* red = &scbuf[0][0];
        for (int i = tid; i < TS * NC; i += BLOCK) {
            float v = red[i] + red[640 + i] + red[1280 + i] + red[1920 + i];
            out[(size_t)s0 * NC + i] = v;
        }
    }
}

} // namespace

extern "C" void kernel_launch(void* const* d_in, const int* in_sizes, int n_in,
                              void* d_out, int out_size, void* d_ws, size_t ws_size,
                              hipStream_t stream) {
    const float* x           = (const float*)d_in[0];
    const float* path_prob   = (const float*)d_in[1];
    const float* W1          = (const float*)d_in[2];
    const float* b1          = (const float*)d_in[3];
    const float* w2          = (const float*)d_in[4];
    const float* b2          = (const float*)d_in[5];
    const float* leaf_logits = (const float*)d_in[6];
    float* out = (float*)d_out;

    const int batch = in_sizes[0] / IN_DIM;                // 32768
    const size_t fragElems = (size_t)NODES * 4 * 64 * 8;   // per precision
    unsigned short* bhi = (unsigned short*)d_ws;
    unsigned short* blo = bhi + fragElems;

    hipLaunchKernelGGL(prep_w1, dim3(NODES), dim3(256), 0, stream, W1, bhi, blo);
    hipLaunchKernelGGL(tree_mfma, dim3(batch / TS), dim3(BLOCK), 0, stream,
                       x, path_prob, W1, b1, w2, b2, leaf_logits, bhi, blo, out);
}

// Round 8
// 180.385 us; speedup vs baseline: 11.2824x; 1.0123x over previous
//
#include <hip/hip_runtime.h>
#include <math.h>

namespace {

typedef __attribute__((ext_vector_type(8))) short bf16x8;
typedef __attribute__((ext_vector_type(4))) float f32x4;

constexpr int IN_DIM = 128;
constexpr int EFF    = 130 * 16;   // W1 node stride (floats)
constexpr int NODES  = 255;
constexpr int TS     = 64;         // samples per block (4 MFMA N-tiles per wave)
constexpr int BLOCK  = 256;
constexpr int NC     = 10;

__device__ inline unsigned short f2bf(float f) {
    unsigned u = __float_as_uint(f);
    u += 0x7fff + ((u >> 16) & 1);          // RNE
    return (unsigned short)(u >> 16);
}
__device__ inline float bf2f(unsigned short h) {
    return __uint_as_float(((unsigned)h) << 16);
}

// ---- prep: W1[:, :128, :] -> MFMA fragment layout, bf16 hi/lo ----
// frag element (n, t, lane l, j): W[k = t*32 + (l>>4)*8 + j][hid = l&15]
__global__ __launch_bounds__(256) void prep_w1(const float* __restrict__ W1,
                                               unsigned short* __restrict__ bhi,
                                               unsigned short* __restrict__ blo) {
    __shared__ float xs[IN_DIM * 16];      // 8 KB: rows 0..127 of this node
    const int n = blockIdx.x, tid = threadIdx.x;
    const float4* src = (const float4*)(W1 + (size_t)n * EFF);
    ((float4*)xs)[tid]       = src[tid];
    ((float4*)xs)[tid + 256] = src[tid + 256];
    __syncthreads();
    const int l = tid & 63, t = tid >> 6;
    const int k0 = t * 32 + (l >> 4) * 8, hid = l & 15;
    bf16x8 hv, lv;
    #pragma unroll
    for (int j = 0; j < 8; ++j) {
        float v = xs[(k0 + j) * 16 + hid];
        unsigned short h = f2bf(v);
        hv[j] = (short)h;
        lv[j] = (short)f2bf(v - bf2f(h));
    }
    ((bf16x8*)bhi)[(n * 4 + t) * 64 + l] = hv;
    ((bf16x8*)blo)[(n * 4 + t) * 64 + l] = lv;
}

// ---- main fused tree kernel ----
// R8: 2-product split (x->bf16, W->hi+lo) = -33% MFMA; cross-node W
// prefetch so no node-iter starts on a cold L2 load; xlbuf deleted.
__global__ __launch_bounds__(BLOCK) __attribute__((amdgpu_waves_per_eu(2, 2)))
void tree_mfma(
    const float* __restrict__ x, const float* __restrict__ path_prob,
    const float* __restrict__ W1, const float* __restrict__ b1,
    const float* __restrict__ w2, const float* __restrict__ b2,
    const float* __restrict__ leaf_logits,
    const unsigned short* __restrict__ bhi, const unsigned short* __restrict__ blo,
    float* __restrict__ out)
{
    __shared__ float pp[128][TS];          // 32 KB: path probs, depths 0..6 only
    // rotating score buffers: buf0 (d=0,3,6): 64 rows @0; buf1 (d=1,4): 16 @64; buf2 (d=2,5): 32 @80
    __shared__ float scbuf[112][TS];       // 28 KB (reused for out-reduction)

    const int tid  = threadIdx.x;
    const int wv   = tid >> 6, l = tid & 63;
    const int quad = l >> 4,   col = l & 15;
    const int s0   = blockIdx.x * TS;

    if (tid < TS) pp[0][tid] = path_prob[s0 + tid];

    // x fragments (bf16 hi only): B operand B[k = t*32+quad*8+j][col]
    bf16x8 xh[4][4];
    #pragma unroll
    for (int t = 0; t < 4; ++t)
        #pragma unroll
        for (int mt = 0; mt < 4; ++mt) {
            const float* xp = x + (size_t)(s0 + mt * 16 + col) * IN_DIM + t * 32 + quad * 8;
            float4 v0 = ((const float4*)xp)[0];
            float4 v1 = ((const float4*)xp)[1];
            float vv[8] = {v0.x, v0.y, v0.z, v0.w, v1.x, v1.y, v1.z, v1.w};
            bf16x8 hv;
            #pragma unroll
            for (int j = 0; j < 8; ++j) hv[j] = (short)f2bf(vv[j]);
            xh[t][mt] = hv;
        }
    // no barrier needed: first cross-wave LDS reads are behind the d0->d1 barrier

    const bf16x8* Wh = (const bf16x8*)bhi;
    const bf16x8* Wl = (const bf16x8*)blo;
    const int wbase[3] = {0, 64, 80};

    // peel: prefetch first node's t=0 fragments (per-wave first node: {0,2,5,6})
    const int first_n = (wv == 0) ? 0 : (wv == 1) ? 2 : (wv == 2) ? 5 : 6;
    bf16x8 wh0 = Wh[(size_t)first_n * 256 + l];
    bf16x8 wl0 = Wl[(size_t)first_n * 256 + l];

    // ---------------- depths 0..6 ----------------
    for (int d = 0; d < 7; ++d) {
        const int nd = 1 << d;
        float (*scW)[TS]  = (float(*)[TS])&scbuf[wbase[d % 3]][0];
        float (*scP)[TS]  = (float(*)[TS])&scbuf[wbase[(d + 2) % 3]][0];   // d-1
        float (*scP2)[TS] = (float(*)[TS])&scbuf[wbase[(d + 1) % 3]][0];   // d-2
        const int stride = 128 >> d, half = 64 >> d;

        for (int nl = wv; nl < nd; nl += 4) {
            const int n = nd - 1 + nl;
            // successor node in this wave's global sequence (crosses depth bound)
            const int nn = (nl + 4 < nd) ? (n + 4) : (2 * nd - 1 + wv);

            // ---- hoisted operands ----
            const float4 b1q = ((const float4*)(b1 + n * 16))[quad];
            const float4 w2q = ((const float4*)(w2 + n * 16))[quad];
            const float4 wpq = ((const float4*)(W1 + (size_t)n * EFF + 128 * 16))[quad];
            const float4 wgq = ((const float4*)(W1 + (size_t)n * EFF + 129 * 16))[quad];
            const float  b2v = b2[n];
            const int    slot = nl * stride;
            const float  ppar = pp[slot][l];
            float par[4], gp[4];
            #pragma unroll
            for (int mt = 0; mt < 4; ++mt) {
                const int scol = mt * 16 + col;
                par[mt] = (d >= 1) ? scP[nl >> 1][scol] : 0.0f;
                gp[mt]  = (d >= 2) ? scP2[nl >> 2][scol] : 0.0f;
            }

            // ---- MFMA t-loop: 2 products, rotating prefetch + succ prefetch ----
            const bf16x8* whp = Wh + (size_t)n * 256 + l;
            const bf16x8* wlp = Wl + (size_t)n * 256 + l;
            bf16x8 whc = wh0, wlc = wl0;

            f32x4 binit = {b1q.x, b1q.y, b1q.z, b1q.w};
            f32x4 acc[4] = {binit, binit, binit, binit};
            #pragma unroll
            for (int t = 0; t < 4; ++t) {
                bf16x8 whn, wln;
                if (t < 3) { whn = whp[(t + 1) * 64]; wln = wlp[(t + 1) * 64]; }
                if (t == 2) {   // prefetch successor's t=0 under remaining MFMA + epilogue
                    wh0 = Wh[(size_t)nn * 256 + l];
                    wl0 = Wl[(size_t)nn * 256 + l];
                }
                #pragma unroll
                for (int mt = 0; mt < 4; ++mt)
                    acc[mt] = __builtin_amdgcn_mfma_f32_16x16x32_bf16(whc, xh[t][mt], acc[mt], 0, 0, 0);
                #pragma unroll
                for (int mt = 0; mt < 4; ++mt)
                    acc[mt] = __builtin_amdgcn_mfma_f32_16x16x32_bf16(wlc, xh[t][mt], acc[mt], 0, 0, 0);
                if (t < 3) { whc = whn; wlc = wln; }
            }

            // epilogue: D[hid=quad*4+r][s=mt*16+col]; hid-reduce = 3 adds + 2 shfls
            float score01[4];
            #pragma unroll
            for (int mt = 0; mt < 4; ++mt) {
                const f32x4 a = acc[mt];
                const float pa = par[mt], ga = gp[mt];
                float ts = 0.0f;
                #pragma unroll
                for (int r = 0; r < 4; ++r) {
                    const float wpr = (r == 0) ? wpq.x : (r == 1) ? wpq.y : (r == 2) ? wpq.z : wpq.w;
                    const float wgr = (r == 0) ? wgq.x : (r == 1) ? wgq.y : (r == 2) ? wgq.z : wgq.w;
                    const float w2r = (r == 0) ? w2q.x : (r == 1) ? w2q.y : (r == 2) ? w2q.z : w2q.w;
                    const float h = fmaf(pa, wpr, fmaf(ga, wgr, a[r]));
                    ts = fmaf(fmaxf(h, 0.0f), w2r, ts);
                }
                ts += __shfl_xor(ts, 16);
                ts += __shfl_xor(ts, 32);
                score01[mt] = ts;
            }
            const float sa = (quad & 1) ? score01[1] : score01[0];
            const float sb = (quad & 1) ? score01[3] : score01[2];
            const float sv = ((quad & 2) ? sb : sa) + b2v;

            scW[nl][l] = sv;
            const float p = 1.0f / (1.0f + __expf(-sv));
            pp[slot][l]        = ppar * p;
            pp[slot + half][l] = ppar * (1.0f - p);
        }
        __syncthreads();
    }

    // ---------------- depth 7: fold leaf mixture, accumulate in VGPRs ----------------
    float oacc[NC];
    #pragma unroll
    for (int c = 0; c < NC; ++c) oacc[c] = 0.0f;
    {
        float (*scP)[TS]  = (float(*)[TS])&scbuf[wbase[0]][0];   // d=6 scores
        float (*scP2)[TS] = (float(*)[TS])&scbuf[wbase[2]][0];   // d=5 scores

        for (int nl = wv; nl < 128; nl += 4) {
            const int n = 127 + nl;
            const int nn = (nl + 4 < 128) ? (n + 4) : 254;   // dummy refetch at end

            const float4 b1q = ((const float4*)(b1 + n * 16))[quad];
            const float4 w2q = ((const float4*)(w2 + n * 16))[quad];
            const float4 wpq = ((const float4*)(W1 + (size_t)n * EFF + 128 * 16))[quad];
            const float4 wgq = ((const float4*)(W1 + (size_t)n * EFF + 129 * 16))[quad];
            const float  b2v = b2[n];
            const float  ppar = pp[nl][l];
            float par[4], gp[4];
            #pragma unroll
            for (int mt = 0; mt < 4; ++mt) {
                const int scol = mt * 16 + col;
                par[mt] = scP[nl >> 1][scol];
                gp[mt]  = scP2[nl >> 2][scol];
            }

            const bf16x8* whp = Wh + (size_t)n * 256 + l;
            const bf16x8* wlp = Wl + (size_t)n * 256 + l;
            bf16x8 whc = wh0, wlc = wl0;

            f32x4 binit = {b1q.x, b1q.y, b1q.z, b1q.w};
            f32x4 acc[4] = {binit, binit, binit, binit};
            #pragma unroll
            for (int t = 0; t < 4; ++t) {
                bf16x8 whn, wln;
                if (t < 3) { whn = whp[(t + 1) * 64]; wln = wlp[(t + 1) * 64]; }
                if (t == 2) {
                    wh0 = Wh[(size_t)nn * 256 + l];
                    wl0 = Wl[(size_t)nn * 256 + l];
                }
                #pragma unroll
                for (int mt = 0; mt < 4; ++mt)
                    acc[mt] = __builtin_amdgcn_mfma_f32_16x16x32_bf16(whc, xh[t][mt], acc[mt], 0, 0, 0);
                #pragma unroll
                for (int mt = 0; mt < 4; ++mt)
                    acc[mt] = __builtin_amdgcn_mfma_f32_16x16x32_bf16(wlc, xh[t][mt], acc[mt], 0, 0, 0);
                if (t < 3) { whc = whn; wlc = wln; }
            }

            float score01[4];
            #pragma unroll
            for (int mt = 0; mt < 4; ++mt) {
                const f32x4 a = acc[mt];
                const float pa = par[mt], ga = gp[mt];
                float ts = 0.0f;
                #pragma unroll
                for (int r = 0; r < 4; ++r) {
                    const float wpr = (r == 0) ? wpq.x : (r == 1) ? wpq.y : (r == 2) ? wpq.z : wpq.w;
                    const float wgr = (r == 0) ? wgq.x : (r == 1) ? wgq.y : (r == 2) ? wgq.z : wgq.w;
                    const float w2r = (r == 0) ? w2q.x : (r == 1) ? w2q.y : (r == 2) ? w2q.z : w2q.w;
                    const float h = fmaf(pa, wpr, fmaf(ga, wgr, a[r]));
                    ts = fmaf(fmaxf(h, 0.0f), w2r, ts);
                }
                ts += __shfl_xor(ts, 16);
                ts += __shfl_xor(ts, 32);
                score01[mt] = ts;
            }
            const float sa = (quad & 1) ? score01[1] : score01[0];
            const float sb = (quad & 1) ? score01[3] : score01[2];
            const float sv = ((quad & 2) ? sb : sa) + b2v;

            const float p = 1.0f / (1.0f + __expf(-sv));
            const float pL = ppar * p;
            const float pR = ppar * (1.0f - p);
            const float* llp = leaf_logits + (size_t)(2 * nl) * NC;
            #pragma unroll
            for (int c = 0; c < NC; ++c)
                oacc[c] = fmaf(pL, llp[c], fmaf(pR, llp[NC + c], oacc[c]));
        }
    }

    // ---------------- cross-wave out reduction through scbuf ----------------
    __syncthreads();
    {
        float* red = &scbuf[0][0];         // 4*64*10 = 2560 floats <= 7168
        #pragma unroll
        for (int c = 0; c < NC; ++c)
            red[(wv * 64 + l) * NC + c] = oacc[c];
    }
    __syncthreads();
    {
        const float* red = &scbuf[0][0];
        for (int i = tid; i < TS * NC; i += BLOCK) {
            float v = red[i] + red[640 + i] + red[1280 + i] + red[1920 + i];
            out[(size_t)s0 * NC + i] = v;
        }
    }
}

} // namespace

extern "C" void kernel_launch(void* const* d_in, const int* in_sizes, int n_in,
                              void* d_out, int out_size, void* d_ws, size_t ws_size,
                              hipStream_t stream) {
    const float* x           = (const float*)d_in[0];
    const float* path_prob   = (const float*)d_in[1];
    const float* W1          = (const float*)d_in[2];
    const float* b1          = (const float*)d_in[3];
    const float* w2          = (const float*)d_in[4];
    const float* b2          = (const float*)d_in[5];
    const float* leaf_logits = (const float*)d_in[6];
    float* out = (float*)d_out;

    const int batch = in_sizes[0] / IN_DIM;                // 32768
    const size_t fragElems = (size_t)NODES * 4 * 64 * 8;   // per precision
    unsigned short* bhi = (unsigned short*)d_ws;
    unsigned short* blo = bhi + fragElems;

    hipLaunchKernelGGL(prep_w1, dim3(NODES), dim3(256), 0, stream, W1, bhi, blo);
    hipLaunchKernelGGL(tree_mfma, dim3(batch / TS), dim3(BLOCK), 0, stream,
                       x, path_prob, W1, b1, w2, b2, leaf_logits, bhi, blo, out);
}

// Round 9
// 151.398 us; speedup vs baseline: 13.4426x; 1.1915x over previous
//
#include <hip/hip_runtime.h>
#include <math.h>

namespace {

typedef __attribute__((ext_vector_type(8))) __fp16 f16x8;
typedef __attribute__((ext_vector_type(4))) float f32x4;

constexpr int IN_DIM = 128;
constexpr int EFF    = 130 * 16;   // W1 node stride (floats)
constexpr int NODES  = 255;
constexpr int TS     = 64;         // samples per block (4 MFMA N-tiles per wave)
constexpr int BLOCK  = 256;
constexpr int NC     = 10;

// ---- prep: W1[:, :128, :] -> MFMA fragment layout, fp16 (single product) ----
// frag element (n, t, lane l, j): W[k = t*32 + (l>>4)*8 + j][hid = l&15]
__global__ __launch_bounds__(256) void prep_w1(const float* __restrict__ W1,
                                               f16x8* __restrict__ wfrag) {
    __shared__ float xs[IN_DIM * 16];      // 8 KB: rows 0..127 of this node
    const int n = blockIdx.x, tid = threadIdx.x;
    const float4* src = (const float4*)(W1 + (size_t)n * EFF);
    ((float4*)xs)[tid]       = src[tid];
    ((float4*)xs)[tid + 256] = src[tid + 256];
    __syncthreads();
    const int l = tid & 63, t = tid >> 6;
    const int k0 = t * 32 + (l >> 4) * 8, hid = l & 15;
    f16x8 hv;
    #pragma unroll
    for (int j = 0; j < 8; ++j)
        hv[j] = (__fp16)xs[(k0 + j) * 16 + hid];   // RNE
    wfrag[(n * 4 + t) * 64 + l] = hv;
}

// ---- main fused tree kernel ----
// R9: fp16 single-product (x,W -> fp16, fp32 accumulate). Error model: RNE
// 2^-11 on both operands -> sigma_h ~ 3.9e-4, ~3x better than R8's bf16
// 2-product, at HALF the MFMA work (16 MFMA / node-iter).
__global__ __launch_bounds__(BLOCK) __attribute__((amdgpu_waves_per_eu(2, 2)))
void tree_mfma(
    const float* __restrict__ x, const float* __restrict__ path_prob,
    const float* __restrict__ W1, const float* __restrict__ b1,
    const float* __restrict__ w2, const float* __restrict__ b2,
    const float* __restrict__ leaf_logits,
    const f16x8* __restrict__ wfrag,
    float* __restrict__ out)
{
    __shared__ float pp[128][TS];          // 32 KB: path probs, depths 0..6 only
    // rotating score buffers: buf0 (d=0,3,6): 64 rows @0; buf1 (d=1,4): 16 @64; buf2 (d=2,5): 32 @80
    __shared__ float scbuf[112][TS];       // 28 KB (reused for out-reduction)

    const int tid  = threadIdx.x;
    const int wv   = tid >> 6, l = tid & 63;
    const int quad = l >> 4,   col = l & 15;
    const int s0   = blockIdx.x * TS;

    if (tid < TS) pp[0][tid] = path_prob[s0 + tid];

    // x fragments (fp16): B operand B[k = t*32+quad*8+j][col]
    f16x8 xh[4][4];
    #pragma unroll
    for (int t = 0; t < 4; ++t)
        #pragma unroll
        for (int mt = 0; mt < 4; ++mt) {
            const float* xp = x + (size_t)(s0 + mt * 16 + col) * IN_DIM + t * 32 + quad * 8;
            float4 v0 = ((const float4*)xp)[0];
            float4 v1 = ((const float4*)xp)[1];
            float vv[8] = {v0.x, v0.y, v0.z, v0.w, v1.x, v1.y, v1.z, v1.w};
            f16x8 hv;
            #pragma unroll
            for (int j = 0; j < 8; ++j) hv[j] = (__fp16)vv[j];
            xh[t][mt] = hv;
        }

    const int wbase[3] = {0, 64, 80};

    // peel: prefetch first node's t=0 fragment (per-wave first node: {0,2,5,6})
    const int first_n = (wv == 0) ? 0 : (wv == 1) ? 2 : (wv == 2) ? 5 : 6;
    f16x8 wh0 = wfrag[(size_t)first_n * 256 + l];

    // ---------------- depths 0..6 ----------------
    for (int d = 0; d < 7; ++d) {
        const int nd = 1 << d;
        float (*scW)[TS]  = (float(*)[TS])&scbuf[wbase[d % 3]][0];
        float (*scP)[TS]  = (float(*)[TS])&scbuf[wbase[(d + 2) % 3]][0];   // d-1
        float (*scP2)[TS] = (float(*)[TS])&scbuf[wbase[(d + 1) % 3]][0];   // d-2
        const int stride = 128 >> d, half = 64 >> d;

        for (int nl = wv; nl < nd; nl += 4) {
            const int n = nd - 1 + nl;
            // successor node in this wave's global sequence (crosses depth bound)
            const int nn = (nl + 4 < nd) ? (n + 4) : (2 * nd - 1 + wv);

            // ---- hoisted operands ----
            const float4 b1q = ((const float4*)(b1 + n * 16))[quad];
            const float4 w2q = ((const float4*)(w2 + n * 16))[quad];
            const float4 wpq = ((const float4*)(W1 + (size_t)n * EFF + 128 * 16))[quad];
            const float4 wgq = ((const float4*)(W1 + (size_t)n * EFF + 129 * 16))[quad];
            const float  b2v = b2[n];
            const int    slot = nl * stride;
            const float  ppar = pp[slot][l];
            float par[4], gp[4];
            #pragma unroll
            for (int mt = 0; mt < 4; ++mt) {
                const int scol = mt * 16 + col;
                par[mt] = (d >= 1) ? scP[nl >> 1][scol] : 0.0f;
                gp[mt]  = (d >= 2) ? scP2[nl >> 2][scol] : 0.0f;
            }

            // ---- MFMA t-loop: 1 product, rotating prefetch + succ prefetch ----
            const f16x8* whp = wfrag + (size_t)n * 256 + l;
            f16x8 whc = wh0;

            f32x4 binit = {b1q.x, b1q.y, b1q.z, b1q.w};
            f32x4 acc[4] = {binit, binit, binit, binit};
            #pragma unroll
            for (int t = 0; t < 4; ++t) {
                f16x8 whn;
                if (t < 3) whn = whp[(t + 1) * 64];
                if (t == 2)    // prefetch successor's t=0 under remaining MFMA + epilogue
                    wh0 = wfrag[(size_t)nn * 256 + l];
                #pragma unroll
                for (int mt = 0; mt < 4; ++mt)
                    acc[mt] = __builtin_amdgcn_mfma_f32_16x16x32_f16(whc, xh[t][mt], acc[mt], 0, 0, 0);
                if (t < 3) whc = whn;
            }

            // epilogue: D[hid=quad*4+r][s=mt*16+col]; hid-reduce = 3 adds + 2 shfls
            float score01[4];
            #pragma unroll
            for (int mt = 0; mt < 4; ++mt) {
                const f32x4 a = acc[mt];
                const float pa = par[mt], ga = gp[mt];
                float ts = 0.0f;
                #pragma unroll
                for (int r = 0; r < 4; ++r) {
                    const float wpr = (r == 0) ? wpq.x : (r == 1) ? wpq.y : (r == 2) ? wpq.z : wpq.w;
                    const float wgr = (r == 0) ? wgq.x : (r == 1) ? wgq.y : (r == 2) ? wgq.z : wgq.w;
                    const float w2r = (r == 0) ? w2q.x : (r == 1) ? w2q.y : (r == 2) ? w2q.z : w2q.w;
                    const float h = fmaf(pa, wpr, fmaf(ga, wgr, a[r]));
                    ts = fmaf(fmaxf(h, 0.0f), w2r, ts);
                }
                ts += __shfl_xor(ts, 16);
                ts += __shfl_xor(ts, 32);
                score01[mt] = ts;
            }
            const float sa = (quad & 1) ? score01[1] : score01[0];
            const float sb = (quad & 1) ? score01[3] : score01[2];
            const float sv = ((quad & 2) ? sb : sa) + b2v;

            scW[nl][l] = sv;
            const float p = 1.0f / (1.0f + __expf(-sv));
            pp[slot][l]        = ppar * p;
            pp[slot + half][l] = ppar * (1.0f - p);
        }
        __syncthreads();
    }

    // ---------------- depth 7: fold leaf mixture, accumulate in VGPRs ----------------
    float oacc[NC];
    #pragma unroll
    for (int c = 0; c < NC; ++c) oacc[c] = 0.0f;
    {
        float (*scP)[TS]  = (float(*)[TS])&scbuf[wbase[0]][0];   // d=6 scores
        float (*scP2)[TS] = (float(*)[TS])&scbuf[wbase[2]][0];   // d=5 scores

        for (int nl = wv; nl < 128; nl += 4) {
            const int n = 127 + nl;
            const int nn = (nl + 4 < 128) ? (n + 4) : 254;   // dummy refetch at end

            const float4 b1q = ((const float4*)(b1 + n * 16))[quad];
            const float4 w2q = ((const float4*)(w2 + n * 16))[quad];
            const float4 wpq = ((const float4*)(W1 + (size_t)n * EFF + 128 * 16))[quad];
            const float4 wgq = ((const float4*)(W1 + (size_t)n * EFF + 129 * 16))[quad];
            const float  b2v = b2[n];
            const float  ppar = pp[nl][l];
            float par[4], gp[4];
            #pragma unroll
            for (int mt = 0; mt < 4; ++mt) {
                const int scol = mt * 16 + col;
                par[mt] = scP[nl >> 1][scol];
                gp[mt]  = scP2[nl >> 2][scol];
            }

            const f16x8* whp = wfrag + (size_t)n * 256 + l;
            f16x8 whc = wh0;

            f32x4 binit = {b1q.x, b1q.y, b1q.z, b1q.w};
            f32x4 acc[4] = {binit, binit, binit, binit};
            #pragma unroll
            for (int t = 0; t < 4; ++t) {
                f16x8 whn;
                if (t < 3) whn = whp[(t + 1) * 64];
                if (t == 2)
                    wh0 = wfrag[(size_t)nn * 256 + l];
                #pragma unroll
                for (int mt = 0; mt < 4; ++mt)
                    acc[mt] = __builtin_amdgcn_mfma_f32_16x16x32_f16(whc, xh[t][mt], acc[mt], 0, 0, 0);
                if (t < 3) whc = whn;
            }

            float score01[4];
            #pragma unroll
            for (int mt = 0; mt < 4; ++mt) {
                const f32x4 a = acc[mt];
                const float pa = par[mt], ga = gp[mt];
                float ts = 0.0f;
                #pragma unroll
                for (int r = 0; r < 4; ++r) {
                    const float wpr = (r == 0) ? wpq.x : (r == 1) ? wpq.y : (r == 2) ? wpq.z : wpq.w;
                    const float wgr = (r == 0) ? wgq.x : (r == 1) ? wgq.y : (r == 2) ? wgq.z : wgq.w;
                    const float w2r = (r == 0) ? w2q.x : (r == 1) ? w2q.y : (r == 2) ? w2q.z : w2q.w;
                    const float h = fmaf(pa, wpr, fmaf(ga, wgr, a[r]));
                    ts = fmaf(fmaxf(h, 0.0f), w2r, ts);
                }
                ts += __shfl_xor(ts, 16);
                ts += __shfl_xor(ts, 32);
                score01[mt] = ts;
            }
            const float sa = (quad & 1) ? score01[1] : score01[0];
            const float sb = (quad & 1) ? score01[3] : score01[2];
            const float sv = ((quad & 2) ? sb : sa) + b2v;

            const float p = 1.0f / (1.0f + __expf(-sv));
            const float pL = ppar * p;
            const float pR = ppar * (1.0f - p);
            const float* llp = leaf_logits + (size_t)(2 * nl) * NC;
            #pragma unroll
            for (int c = 0; c < NC; ++c)
                oacc[c] = fmaf(pL, llp[c], fmaf(pR, llp[NC + c], oacc[c]));
        }
    }

    // ---------------- cross-wave out reduction through scbuf ----------------
    __syncthreads();
    {
        float* red = &scbuf[0][0];         // 4*64*10 = 2560 floats <= 7168
        #pragma unroll
        for (int c = 0; c < NC; ++c)
            red[(wv * 64 + l) * NC + c] = oacc[c];
    }
    __syncthreads();
    {
        const float* red = &scbuf[0][0];
        for (int i = tid; i < TS * NC; i += BLOCK) {
            float v = red[i] + red[640 + i] + red[1280 + i] + red[1920 + i];
            out[(size_t)s0 * NC + i] = v;
        }
    }
}

} // namespace

extern "C" void kernel_launch(void* const* d_in, const int* in_sizes, int n_in,
                              void* d_out, int out_size, void* d_ws, size_t ws_size,
                              hipStream_t stream) {
    const float* x           = (const float*)d_in[0];
    const float* path_prob   = (const float*)d_in[1];
    const float* W1          = (const float*)d_in[2];
    const float* b1          = (const float*)d_in[3];
    const float* w2          = (const float*)d_in[4];
    const float* b2          = (const float*)d_in[5];
    const float* leaf_logits = (const float*)d_in[6];
    float* out = (float*)d_out;

    const int batch = in_sizes[0] / IN_DIM;                // 32768
    f16x8* wfrag = (f16x8*)d_ws;                           // 255*4*64*16B ~= 1.04 MB

    hipLaunchKernelGGL(prep_w1, dim3(NODES), dim3(256), 0, stream, W1, wfrag);
    hipLaunchKernelGGL(tree_mfma, dim3(batch / TS), dim3(BLOCK), 0, stream,
                       x, path_prob, W1, b1, w2, b2, leaf_logits, wfrag, out);
}